// Round 5
// baseline (364.264 us; speedup 1.0000x reference)
//
#include <hip/hip_runtime.h>
#include <stdint.h>

// ---------------------------------------------------------------------------
// TTLinearAttention on MI355X. Inputs fp32, OUTPUT FP32 (round-4 finding:
// harness reads d_out as float32; earlier bf16 writes scrambled the readback).
// Pipeline (peak ws = 136 MiB):
//   0) cvt: query fp32->bf16; cvt4: 4 weight matrices fp32->bf16
//   1) gemm_bt<false> z=0..2: phiQ/phiK/V = phi?(q @ W^T + b) -> bf16 ws
//   2) kv_outer: partial S^T[j][i] = sum_l phiK[l,i] V[l,j], Z[i] (fp32, split 4)
//   3) ctx_kernel: sum partials -> LDS bf16 [S^T | Z | 0], num+denom via MFMA
//      (5th n-frag = Z column gives denom), ctx = num/denom -> bf16 (alias phiK)
//   4) gemm_bt<true> z=0: out = ctx @ Wo^T + bo -> d_out (FP32)
// Layouts: activations [tok=16384][E=1024] row-major bf16; head (b,h) is the
// column block h*64..h*64+63 of rows b*4096..+4095.
// ---------------------------------------------------------------------------

typedef __attribute__((ext_vector_type(8))) short short8;
typedef __attribute__((ext_vector_type(4))) float f32x4;
typedef __attribute__((ext_vector_type(4))) unsigned short us4;
typedef __attribute__((ext_vector_type(8))) unsigned short us8;

#define E_DIM 1024
#define LSEQ 4096
#define NTOK 16384
#define DH 64
#define NSPLIT 4
#define ROWS_PER_SPLIT (LSEQ / NSPLIT) // 1024

__device__ __forceinline__ float b2f(unsigned short u) {
    return __builtin_bit_cast(float, (uint32_t)u << 16);
}
__device__ __forceinline__ unsigned short f2b(float f) {
    uint32_t x = __builtin_bit_cast(uint32_t, f);
    x += 0x7FFFu + ((x >> 16) & 1u); // round-to-nearest-even
    return (unsigned short)(x >> 16);
}
__device__ __forceinline__ void gload16(const void* g, void* l) {
    __builtin_amdgcn_global_load_lds(
        (const __attribute__((address_space(1))) void*)g,
        (__attribute__((address_space(3))) void*)l, 16, 0, 0);
}

// ---------------------------------------------------------------------------
__global__ __launch_bounds__(256) void cvt_f32_bf16(
    const float* __restrict__ s, unsigned short* __restrict__ d, int n8)
{
    int i = blockIdx.x * 256 + threadIdx.x;
    const int stride = gridDim.x * 256;
    for (; i < n8; i += stride) {
        f32x4 a = ((const f32x4*)s)[(size_t)i * 2];
        f32x4 b = ((const f32x4*)s)[(size_t)i * 2 + 1];
        us8 o = { f2b(a.x), f2b(a.y), f2b(a.z), f2b(a.w),
                  f2b(b.x), f2b(b.y), f2b(b.z), f2b(b.w) };
        ((us8*)d)[i] = o;
    }
}

__global__ __launch_bounds__(256) void cvt4_f32_bf16(
    const float* __restrict__ s0, const float* __restrict__ s1,
    const float* __restrict__ s2, const float* __restrict__ s3,
    unsigned short* __restrict__ d0, unsigned short* __restrict__ d1,
    unsigned short* __restrict__ d2, unsigned short* __restrict__ d3, int n8)
{
    const int z = blockIdx.z;
    const float* s = (z == 0) ? s0 : (z == 1) ? s1 : (z == 2) ? s2 : s3;
    unsigned short* d = (z == 0) ? d0 : (z == 1) ? d1 : (z == 2) ? d2 : d3;
    int i = blockIdx.x * 256 + threadIdx.x;
    const int stride = gridDim.x * 256;
    for (; i < n8; i += stride) {
        f32x4 a = ((const f32x4*)s)[(size_t)i * 2];
        f32x4 b = ((const f32x4*)s)[(size_t)i * 2 + 1];
        us8 o = { f2b(a.x), f2b(a.y), f2b(a.z), f2b(a.w),
                  f2b(b.x), f2b(b.y), f2b(b.z), f2b(b.w) };
        ((us8*)d)[i] = o;
    }
}

// ---------------------------------------------------------------------------
// GEMM: C[m,n] = phi?( sum_k A[m,k] * W[n,k] + bias[n] )   (bias fp32)
// A,W bf16 via global_load_lds (m97 structure). OUTF32 picks output dtype.
// M=16384 (grid.y*128), N=1024 (grid.x*128), K=1024. 256 threads = 4 waves,
// wave (wr,wc) owns 64x64; 16x16x32 bf16 MFMA; BK=64.
// ---------------------------------------------------------------------------
template <bool OUTF32>
__global__ __launch_bounds__(256) void gemm_bt(
    const unsigned short* __restrict__ A,
    const unsigned short* __restrict__ W0, const unsigned short* __restrict__ W1,
    const unsigned short* __restrict__ W2,
    const float* __restrict__ b0, const float* __restrict__ b1,
    const float* __restrict__ b2,
    void* __restrict__ o0, void* __restrict__ o1, void* __restrict__ o2,
    int nphi)
{
    __shared__ unsigned short As[128 * 64];
    __shared__ unsigned short Bs[128 * 64];

    const int z = blockIdx.z;
    const unsigned short* W = (z == 0) ? W0 : ((z == 1) ? W1 : W2);
    const float* bias       = (z == 0) ? b0 : ((z == 1) ? b1 : b2);
    void* out               = (z == 0) ? o0 : ((z == 1) ? o1 : o2);
    const bool phi = z < nphi;

    const int tid  = threadIdx.x;
    const int lane = tid & 63;
    const int w    = tid >> 6;
    const int wr   = w >> 1, wc = w & 1;
    const int m0   = blockIdx.y * 128;
    const int n0   = blockIdx.x * 128;

    // staging: each wave deposits 64 lanes x 16B = 8 rows x 128B per call
    const int srow = w * 8 + (lane >> 3); // row within 32-row chunk
    const int scol = (lane & 7) * 8;      // k-offset in elements

    f32x4 acc[4][4] = {};

    for (int kt = 0; kt < 16; ++kt) {
        const int k0 = kt * 64;
#pragma unroll
        for (int c = 0; c < 4; ++c) {
            const int r = c * 32 + srow;
            gload16(&A[(size_t)(m0 + r) * E_DIM + k0 + scol], &As[(c * 32 + w * 8) * 64]);
            gload16(&W[(size_t)(n0 + r) * E_DIM + k0 + scol], &Bs[(c * 32 + w * 8) * 64]);
        }
        __syncthreads();
#pragma unroll
        for (int kk = 0; kk < 2; ++kk) {
            const int krd = kk * 32 + (lane >> 4) * 8;
            short8 af[4], bfr[4];
#pragma unroll
            for (int mi = 0; mi < 4; ++mi)
                af[mi] = *(const short8*)&As[(wr * 64 + mi * 16 + (lane & 15)) * 64 + krd];
#pragma unroll
            for (int ni = 0; ni < 4; ++ni)
                bfr[ni] = *(const short8*)&Bs[(wc * 64 + ni * 16 + (lane & 15)) * 64 + krd];
#pragma unroll
            for (int mi = 0; mi < 4; ++mi)
#pragma unroll
                for (int ni = 0; ni < 4; ++ni)
                    acc[mi][ni] = __builtin_amdgcn_mfma_f32_16x16x32_bf16(
                        af[mi], bfr[ni], acc[mi][ni], 0, 0, 0);
        }
        __syncthreads();
    }

    // epilogue: C/D layout col=lane&15, row=(lane>>4)*4+r
#pragma unroll
    for (int mi = 0; mi < 4; ++mi) {
        const int rbase = m0 + wr * 64 + mi * 16 + ((lane >> 4) << 2);
#pragma unroll
        for (int ni = 0; ni < 4; ++ni) {
            const int col = n0 + wc * 64 + ni * 16 + (lane & 15);
            const float bv = bias[col];
#pragma unroll
            for (int r = 0; r < 4; ++r) {
                float v = acc[mi][ni][r] + bv;
                if (phi) v = (v > 0.f) ? (v + 1.f) : __expf(v); // elu(v)+1
                if (OUTF32)
                    ((float*)out)[(size_t)(rbase + r) * E_DIM + col] = v;
                else
                    ((unsigned short*)out)[(size_t)(rbase + r) * E_DIM + col] = f2b(v);
            }
        }
    }
}

// ---------------------------------------------------------------------------
// kv_outer: per (b,h,split) partial S^T[j][i] = sum_l phiK[l,i]*V[l,j], Z[i].
// 256 threads; thread (i0=(t&15)*4, j0=(t>>4)*4) owns a 4x4 outer-product tile.
// ---------------------------------------------------------------------------
__global__ __launch_bounds__(256) void kv_outer(
    const unsigned short* __restrict__ K, const unsigned short* __restrict__ V,
    float* __restrict__ Sp, float* __restrict__ Zp)
{
    __shared__ float kb[8][64];
    __shared__ float vb[8][64];
    const int split = blockIdx.x;
    const int bh    = blockIdx.y;
    const int b = bh >> 4, h = bh & 15;
    const int t  = threadIdx.x;
    const int i0 = (t & 15) * 4;
    const int j0 = (t >> 4) * 4;
    const int sr = t >> 5;
    const int sc = (t & 31) * 4;

    const unsigned short* sbase = (sc < 64) ? K : V;
    size_t gbase = ((size_t)(b * LSEQ + split * ROWS_PER_SPLIT)) * E_DIM + h * DH;

    f32x4 acc[4] = {};
    f32x4 zacc = {};

    for (int chunk = 0; chunk < ROWS_PER_SPLIT / 8; ++chunk) {
        us4 u = *(const us4*)&sbase[gbase + (size_t)sr * E_DIM + (sc & 63)];
        f32x4 fv = { b2f(u.x), b2f(u.y), b2f(u.z), b2f(u.w) };
        float* dst = (sc < 64) ? &kb[sr][sc] : &vb[sr][sc - 64];
        *(f32x4*)dst = fv;
        __syncthreads();
#pragma unroll
        for (int rr = 0; rr < 8; ++rr) {
            f32x4 kv = *(const f32x4*)&kb[rr][i0];
            f32x4 vv = *(const f32x4*)&vb[rr][j0];
            acc[0] += kv * vv.x;
            acc[1] += kv * vv.y;
            acc[2] += kv * vv.z;
            acc[3] += kv * vv.w;
            if ((t >> 4) == 0) zacc += kv;
        }
        __syncthreads();
        gbase += (size_t)8 * E_DIM;
    }

    const size_t sb = ((size_t)bh * NSPLIT + split) * (DH * DH);
#pragma unroll
    for (int jj = 0; jj < 4; ++jj)
        *(f32x4*)&Sp[sb + (size_t)(j0 + jj) * DH + i0] = acc[jj];
    if ((t >> 4) == 0)
        *(f32x4*)&Zp[((size_t)bh * NSPLIT + split) * DH + i0] = zacc;
}

// ---------------------------------------------------------------------------
// ctx_kernel: per (b,h): B-tile = [S^T (64 rows) | Z (row 64) | zeros (65..79)]
// bf16 in LDS. num+denom via MFMA (5 n-frags, K=64); ctx = num/(denom+eps).
// Each block: 256 rows of phiQ (wave w -> 64 rows).
// ---------------------------------------------------------------------------
__global__ __launch_bounds__(256) void ctx_kernel(
    const unsigned short* __restrict__ Q, const float* __restrict__ Sp,
    const float* __restrict__ Zp, unsigned short* __restrict__ ctx)
{
    __shared__ unsigned short Bs[80 * 64];
    const int bh = blockIdx.y;
    const int b = bh >> 4, h = bh & 15;
    const int t    = threadIdx.x;
    const int lane = t & 63;
    const int w    = t >> 6;

    for (int e = t; e < 4096; e += 256) {
        float s = 0.f;
#pragma unroll
        for (int p = 0; p < NSPLIT; ++p)
            s += Sp[((size_t)bh * NSPLIT + p) * (DH * DH) + e];
        Bs[e] = f2b(s);
    }
    if (t < 64) {
        float zv = 0.f;
#pragma unroll
        for (int p = 0; p < NSPLIT; ++p)
            zv += Zp[((size_t)bh * NSPLIT + p) * DH + t];
        Bs[64 * 64 + t] = f2b(zv);
    }
    for (int e = t; e < 15 * 64; e += 256) Bs[65 * 64 + e] = 0;
    __syncthreads();

    const int m0 = blockIdx.x * 256 + w * 64;
    f32x4 acc[4][5] = {};
#pragma unroll
    for (int kk = 0; kk < 2; ++kk) {
        const int krd = kk * 32 + (lane >> 4) * 8;
        short8 af[4];
#pragma unroll
        for (int mi = 0; mi < 4; ++mi) {
            const int l = m0 + mi * 16 + (lane & 15);
            af[mi] = *(const short8*)&Q[((size_t)(b * LSEQ + l)) * E_DIM + h * DH + krd];
        }
#pragma unroll
        for (int ni = 0; ni < 5; ++ni) {
            short8 bfr = *(const short8*)&Bs[(ni * 16 + (lane & 15)) * 64 + krd];
#pragma unroll
            for (int mi = 0; mi < 4; ++mi)
                acc[mi][ni] = __builtin_amdgcn_mfma_f32_16x16x32_bf16(
                    af[mi], bfr, acc[mi][ni], 0, 0, 0);
        }
    }
#pragma unroll
    for (int mi = 0; mi < 4; ++mi) {
#pragma unroll
        for (int r = 0; r < 4; ++r) {
            const float dv  = __shfl(acc[mi][4][r], lane & 48, 64); // denom (col 64)
            const float inv = 1.f / (dv + 1e-6f);
            const int l = m0 + mi * 16 + ((lane >> 4) << 2) + r;
#pragma unroll
            for (int ni = 0; ni < 4; ++ni)
                ctx[((size_t)(b * LSEQ + l)) * E_DIM + h * DH + ni * 16 + (lane & 15)] =
                    f2b(acc[mi][ni][r] * inv);
        }
    }
}

// ---------------------------------------------------------------------------
extern "C" void kernel_launch(void* const* d_in, const int* in_sizes, int n_in,
                              void* d_out, int out_size, void* d_ws, size_t ws_size,
                              hipStream_t stream)
{
    const float* query = (const float*)d_in[0];
    const float* Wq = (const float*)d_in[1];
    const float* bq = (const float*)d_in[2];
    const float* Wk = (const float*)d_in[3];
    const float* bk = (const float*)d_in[4];
    const float* Wv = (const float*)d_in[5];
    const float* bv = (const float*)d_in[6];
    const float* Wo = (const float*)d_in[7];
    const float* bo = (const float*)d_in[8];

    // ws (136 MiB peak):
    //   [qb 32MiB | Wob 2 | Wqb 2 | Wkb 2 | Wvb 2 | phiQ 32 | phiK 32 | Vw 32]
    //   Sp/Zp (4.07 MiB) alias Wqb..Wvb after gemm1; ctx aliases phiK.
    unsigned short* qb   = (unsigned short*)d_ws;
    unsigned short* Wob  = qb  + (size_t)NTOK * E_DIM;
    unsigned short* Wqb  = Wob + (size_t)E_DIM * E_DIM;
    unsigned short* Wkb  = Wqb + (size_t)E_DIM * E_DIM;
    unsigned short* Wvb  = Wkb + (size_t)E_DIM * E_DIM;
    unsigned short* phiQ = Wvb + (size_t)E_DIM * E_DIM;
    unsigned short* phiK = phiQ + (size_t)NTOK * E_DIM;
    unsigned short* Vw   = phiK + (size_t)NTOK * E_DIM;
    float* Sp = (float*)Wqb;                          // [64][NSPLIT][64*64] f32
    float* Zp = Sp + (size_t)64 * NSPLIT * DH * DH;   // [64][NSPLIT][64] f32
    unsigned short* ctx = phiK;                       // phiK dead after kv_outer

    // 0) fp32 -> bf16
    cvt_f32_bf16<<<dim3(2048), 256, 0, stream>>>(query, qb, NTOK * E_DIM / 8);
    cvt4_f32_bf16<<<dim3(512, 1, 4), 256, 0, stream>>>(Wq, Wk, Wv, Wo,
                                                       Wqb, Wkb, Wvb, Wob,
                                                       E_DIM * E_DIM / 8);
    // 1) QKV projections (+phi on Q,K) -> bf16
    gemm_bt<false><<<dim3(8, 128, 3), 256, 0, stream>>>(qb, Wqb, Wkb, Wvb,
                                                        bq, bk, bv,
                                                        phiQ, phiK, Vw, 2);
    // 2) S^T/Z partials (Sp/Zp overwrite dead Wqb..Wvb)
    kv_outer<<<dim3(NSPLIT, 64), 256, 0, stream>>>(phiK, Vw, Sp, Zp);
    // 3) context -> bf16
    ctx_kernel<<<dim3(LSEQ / 256, 64), 256, 0, stream>>>(phiQ, Sp, Zp, ctx);
    // 4) output projection -> FP32 d_out
    gemm_bt<true><<<dim3(8, 128, 1), 256, 0, stream>>>(ctx, Wob, Wob, Wob,
                                                       bo, bo, bo,
                                                       d_out, d_out, d_out, 0);
}

// Round 6
// 360.254 us; speedup vs baseline: 1.0111x; 1.0111x over previous
//
#include <hip/hip_runtime.h>
#include <stdint.h>

// ---------------------------------------------------------------------------
// TTLinearAttention on MI355X. Inputs fp32, output fp32.
// Round 6: + T1 XCD-aware block swizzle on both GEMMs (z-fastest decode:
// each XCD owns contiguous m-tile range for ALL n,z -> A-tile fetched by
// exactly one XCD; predicted FETCH_SIZE 399 MB -> ~90 MB on QKV GEMM).
// Pipeline (peak ws = 136 MiB):
//   0) cvt: query fp32->bf16; cvt4: 4 weight matrices fp32->bf16
//   1) gemm_bt<false,3>: phiQ/phiK/V = phi?(q @ W^T + b) -> bf16 ws
//   2) kv_outer: partial S^T[j][i] = sum_l phiK[l,i] V[l,j], Z[i] (fp32, split 4)
//   3) ctx_kernel: sum partials -> LDS bf16 [S^T | Z | 0], num+denom via MFMA
//   4) gemm_bt<true,1>: out = ctx @ Wo^T + bo -> d_out (FP32)
// ---------------------------------------------------------------------------

typedef __attribute__((ext_vector_type(8))) short short8;
typedef __attribute__((ext_vector_type(4))) float f32x4;
typedef __attribute__((ext_vector_type(4))) unsigned short us4;
typedef __attribute__((ext_vector_type(8))) unsigned short us8;

#define E_DIM 1024
#define LSEQ 4096
#define NTOK 16384
#define DH 64
#define NSPLIT 4
#define ROWS_PER_SPLIT (LSEQ / NSPLIT) // 1024

__device__ __forceinline__ float b2f(unsigned short u) {
    return __builtin_bit_cast(float, (uint32_t)u << 16);
}
__device__ __forceinline__ unsigned short f2b(float f) {
    uint32_t x = __builtin_bit_cast(uint32_t, f);
    x += 0x7FFFu + ((x >> 16) & 1u); // round-to-nearest-even
    return (unsigned short)(x >> 16);
}
__device__ __forceinline__ void gload16(const void* g, void* l) {
    __builtin_amdgcn_global_load_lds(
        (const __attribute__((address_space(1))) void*)g,
        (__attribute__((address_space(3))) void*)l, 16, 0, 0);
}

// ---------------------------------------------------------------------------
__global__ __launch_bounds__(256) void cvt_f32_bf16(
    const float* __restrict__ s, unsigned short* __restrict__ d, int n8)
{
    int i = blockIdx.x * 256 + threadIdx.x;
    const int stride = gridDim.x * 256;
    for (; i < n8; i += stride) {
        f32x4 a = ((const f32x4*)s)[(size_t)i * 2];
        f32x4 b = ((const f32x4*)s)[(size_t)i * 2 + 1];
        us8 o = { f2b(a.x), f2b(a.y), f2b(a.z), f2b(a.w),
                  f2b(b.x), f2b(b.y), f2b(b.z), f2b(b.w) };
        ((us8*)d)[i] = o;
    }
}

__global__ __launch_bounds__(256) void cvt4_f32_bf16(
    const float* __restrict__ s0, const float* __restrict__ s1,
    const float* __restrict__ s2, const float* __restrict__ s3,
    unsigned short* __restrict__ d0, unsigned short* __restrict__ d1,
    unsigned short* __restrict__ d2, unsigned short* __restrict__ d3, int n8)
{
    const int z = blockIdx.z;
    const float* s = (z == 0) ? s0 : (z == 1) ? s1 : (z == 2) ? s2 : s3;
    unsigned short* d = (z == 0) ? d0 : (z == 1) ? d1 : (z == 2) ? d2 : d3;
    int i = blockIdx.x * 256 + threadIdx.x;
    const int stride = gridDim.x * 256;
    for (; i < n8; i += stride) {
        f32x4 a = ((const f32x4*)s)[(size_t)i * 2];
        f32x4 b = ((const f32x4*)s)[(size_t)i * 2 + 1];
        us8 o = { f2b(a.x), f2b(a.y), f2b(a.z), f2b(a.w),
                  f2b(b.x), f2b(b.y), f2b(b.z), f2b(b.w) };
        ((us8*)d)[i] = o;
    }
}

// ---------------------------------------------------------------------------
// GEMM: C[m,n] = phi?( sum_k A[m,k] * W[n,k] + bias[n] )   (bias fp32)
// A,W bf16 via global_load_lds (m97 structure). OUTF32 picks output dtype.
// 1D grid of 1024*NZ blocks, XCD-swizzled:
//   xcd = bid%8 (HW round-robin), chunk idx = bid/8, swz = xcd*(128*NZ)+idx;
//   m = swz/(8*NZ) (slowest), rem = swz%(8*NZ), n = rem%8, z = rem/8.
// => XCD k owns m-tiles [16k,16k+16) for ALL (n,z): each 256KB A-tile is
//    read by exactly one XCD, its 8*NZ sharers temporally adjacent (L2-hit).
// ---------------------------------------------------------------------------
template <bool OUTF32, int NZ>
__global__ __launch_bounds__(256) void gemm_bt(
    const unsigned short* __restrict__ A,
    const unsigned short* __restrict__ W0, const unsigned short* __restrict__ W1,
    const unsigned short* __restrict__ W2,
    const float* __restrict__ b0, const float* __restrict__ b1,
    const float* __restrict__ b2,
    void* __restrict__ o0, void* __restrict__ o1, void* __restrict__ o2,
    int nphi)
{
    __shared__ unsigned short As[128 * 64];
    __shared__ unsigned short Bs[128 * 64];

    // --- T1 XCD swizzle (bijective: nwg = 1024*NZ, divisible by 8) ---
    const int bid = blockIdx.x;
    const int swz = (bid & 7) * (128 * NZ) + (bid >> 3);
    const int mt  = swz / (8 * NZ);
    const int rem = swz % (8 * NZ);
    const int nt  = rem & 7;
    const int z   = rem >> 3;

    const unsigned short* W = (z == 0) ? W0 : ((z == 1) ? W1 : W2);
    const float* bias       = (z == 0) ? b0 : ((z == 1) ? b1 : b2);
    void* out               = (z == 0) ? o0 : ((z == 1) ? o1 : o2);
    const bool phi = z < nphi;

    const int tid  = threadIdx.x;
    const int lane = tid & 63;
    const int w    = tid >> 6;
    const int wr   = w >> 1, wc = w & 1;
    const int m0   = mt * 128;
    const int n0   = nt * 128;

    // staging: each wave deposits 64 lanes x 16B = 8 rows x 128B per call
    const int srow = w * 8 + (lane >> 3); // row within 32-row chunk
    const int scol = (lane & 7) * 8;      // k-offset in elements

    f32x4 acc[4][4] = {};

    for (int kt = 0; kt < 16; ++kt) {
        const int k0 = kt * 64;
#pragma unroll
        for (int c = 0; c < 4; ++c) {
            const int r = c * 32 + srow;
            gload16(&A[(size_t)(m0 + r) * E_DIM + k0 + scol], &As[(c * 32 + w * 8) * 64]);
            gload16(&W[(size_t)(n0 + r) * E_DIM + k0 + scol], &Bs[(c * 32 + w * 8) * 64]);
        }
        __syncthreads();
#pragma unroll
        for (int kk = 0; kk < 2; ++kk) {
            const int krd = kk * 32 + (lane >> 4) * 8;
            short8 af[4], bfr[4];
#pragma unroll
            for (int mi = 0; mi < 4; ++mi)
                af[mi] = *(const short8*)&As[(wr * 64 + mi * 16 + (lane & 15)) * 64 + krd];
#pragma unroll
            for (int ni = 0; ni < 4; ++ni)
                bfr[ni] = *(const short8*)&Bs[(wc * 64 + ni * 16 + (lane & 15)) * 64 + krd];
#pragma unroll
            for (int mi = 0; mi < 4; ++mi)
#pragma unroll
                for (int ni = 0; ni < 4; ++ni)
                    acc[mi][ni] = __builtin_amdgcn_mfma_f32_16x16x32_bf16(
                        af[mi], bfr[ni], acc[mi][ni], 0, 0, 0);
        }
        __syncthreads();
    }

    // epilogue: C/D layout col=lane&15, row=(lane>>4)*4+r
#pragma unroll
    for (int mi = 0; mi < 4; ++mi) {
        const int rbase = m0 + wr * 64 + mi * 16 + ((lane >> 4) << 2);
#pragma unroll
        for (int ni = 0; ni < 4; ++ni) {
            const int col = n0 + wc * 64 + ni * 16 + (lane & 15);
            const float bv = bias[col];
#pragma unroll
            for (int r = 0; r < 4; ++r) {
                float v = acc[mi][ni][r] + bv;
                if (phi) v = (v > 0.f) ? (v + 1.f) : __expf(v); // elu(v)+1
                if (OUTF32)
                    ((float*)out)[(size_t)(rbase + r) * E_DIM + col] = v;
                else
                    ((unsigned short*)out)[(size_t)(rbase + r) * E_DIM + col] = f2b(v);
            }
        }
    }
}

// ---------------------------------------------------------------------------
// kv_outer: per (b,h,split) partial S^T[j][i] = sum_l phiK[l,i]*V[l,j], Z[i].
// 256 threads; thread (i0=(t&15)*4, j0=(t>>4)*4) owns a 4x4 outer-product tile.
// ---------------------------------------------------------------------------
__global__ __launch_bounds__(256) void kv_outer(
    const unsigned short* __restrict__ K, const unsigned short* __restrict__ V,
    float* __restrict__ Sp, float* __restrict__ Zp)
{
    __shared__ float kb[8][64];
    __shared__ float vb[8][64];
    const int split = blockIdx.x;
    const int bh    = blockIdx.y;
    const int b = bh >> 4, h = bh & 15;
    const int t  = threadIdx.x;
    const int i0 = (t & 15) * 4;
    const int j0 = (t >> 4) * 4;
    const int sr = t >> 5;
    const int sc = (t & 31) * 4;

    const unsigned short* sbase = (sc < 64) ? K : V;
    size_t gbase = ((size_t)(b * LSEQ + split * ROWS_PER_SPLIT)) * E_DIM + h * DH;

    f32x4 acc[4] = {};
    f32x4 zacc = {};

    for (int chunk = 0; chunk < ROWS_PER_SPLIT / 8; ++chunk) {
        us4 u = *(const us4*)&sbase[gbase + (size_t)sr * E_DIM + (sc & 63)];
        f32x4 fv = { b2f(u.x), b2f(u.y), b2f(u.z), b2f(u.w) };
        float* dst = (sc < 64) ? &kb[sr][sc] : &vb[sr][sc - 64];
        *(f32x4*)dst = fv;
        __syncthreads();
#pragma unroll
        for (int rr = 0; rr < 8; ++rr) {
            f32x4 kv = *(const f32x4*)&kb[rr][i0];
            f32x4 vv = *(const f32x4*)&vb[rr][j0];
            acc[0] += kv * vv.x;
            acc[1] += kv * vv.y;
            acc[2] += kv * vv.z;
            acc[3] += kv * vv.w;
            if ((t >> 4) == 0) zacc += kv;
        }
        __syncthreads();
        gbase += (size_t)8 * E_DIM;
    }

    const size_t sb = ((size_t)bh * NSPLIT + split) * (DH * DH);
#pragma unroll
    for (int jj = 0; jj < 4; ++jj)
        *(f32x4*)&Sp[sb + (size_t)(j0 + jj) * DH + i0] = acc[jj];
    if ((t >> 4) == 0)
        *(f32x4*)&Zp[((size_t)bh * NSPLIT + split) * DH + i0] = zacc;
}

// ---------------------------------------------------------------------------
// ctx_kernel: per (b,h): B-tile = [S^T (64 rows) | Z (row 64) | zeros (65..79)]
// bf16 in LDS. num+denom via MFMA (5 n-frags, K=64); ctx = num/(denom+eps).
// Each block: 256 rows of phiQ (wave w -> 64 rows).
// ---------------------------------------------------------------------------
__global__ __launch_bounds__(256) void ctx_kernel(
    const unsigned short* __restrict__ Q, const float* __restrict__ Sp,
    const float* __restrict__ Zp, unsigned short* __restrict__ ctx)
{
    __shared__ unsigned short Bs[80 * 64];
    const int bh = blockIdx.y;
    const int b = bh >> 4, h = bh & 15;
    const int t    = threadIdx.x;
    const int lane = t & 63;
    const int w    = t >> 6;

    for (int e = t; e < 4096; e += 256) {
        float s = 0.f;
#pragma unroll
        for (int p = 0; p < NSPLIT; ++p)
            s += Sp[((size_t)bh * NSPLIT + p) * (DH * DH) + e];
        Bs[e] = f2b(s);
    }
    if (t < 64) {
        float zv = 0.f;
#pragma unroll
        for (int p = 0; p < NSPLIT; ++p)
            zv += Zp[((size_t)bh * NSPLIT + p) * DH + t];
        Bs[64 * 64 + t] = f2b(zv);
    }
    for (int e = t; e < 15 * 64; e += 256) Bs[65 * 64 + e] = 0;
    __syncthreads();

    const int m0 = blockIdx.x * 256 + w * 64;
    f32x4 acc[4][5] = {};
#pragma unroll
    for (int kk = 0; kk < 2; ++kk) {
        const int krd = kk * 32 + (lane >> 4) * 8;
        short8 af[4];
#pragma unroll
        for (int mi = 0; mi < 4; ++mi) {
            const int l = m0 + mi * 16 + (lane & 15);
            af[mi] = *(const short8*)&Q[((size_t)(b * LSEQ + l)) * E_DIM + h * DH + krd];
        }
#pragma unroll
        for (int ni = 0; ni < 5; ++ni) {
            short8 bfr = *(const short8*)&Bs[(ni * 16 + (lane & 15)) * 64 + krd];
#pragma unroll
            for (int mi = 0; mi < 4; ++mi)
                acc[mi][ni] = __builtin_amdgcn_mfma_f32_16x16x32_bf16(
                    af[mi], bfr, acc[mi][ni], 0, 0, 0);
        }
    }
#pragma unroll
    for (int mi = 0; mi < 4; ++mi) {
#pragma unroll
        for (int r = 0; r < 4; ++r) {
            const float dv  = __shfl(acc[mi][4][r], lane & 48, 64); // denom (col 64)
            const float inv = 1.f / (dv + 1e-6f);
            const int l = m0 + mi * 16 + ((lane >> 4) << 2) + r;
#pragma unroll
            for (int ni = 0; ni < 4; ++ni)
                ctx[((size_t)(b * LSEQ + l)) * E_DIM + h * DH + ni * 16 + (lane & 15)] =
                    f2b(acc[mi][ni][r] * inv);
        }
    }
}

// ---------------------------------------------------------------------------
extern "C" void kernel_launch(void* const* d_in, const int* in_sizes, int n_in,
                              void* d_out, int out_size, void* d_ws, size_t ws_size,
                              hipStream_t stream)
{
    const float* query = (const float*)d_in[0];
    const float* Wq = (const float*)d_in[1];
    const float* bq = (const float*)d_in[2];
    const float* Wk = (const float*)d_in[3];
    const float* bk = (const float*)d_in[4];
    const float* Wv = (const float*)d_in[5];
    const float* bv = (const float*)d_in[6];
    const float* Wo = (const float*)d_in[7];
    const float* bo = (const float*)d_in[8];

    // ws (136 MiB peak):
    //   [qb 32MiB | Wob 2 | Wqb 2 | Wkb 2 | Wvb 2 | phiQ 32 | phiK 32 | Vw 32]
    //   Sp/Zp (4.07 MiB) alias Wqb..Wvb after gemm1; ctx aliases phiK.
    unsigned short* qb   = (unsigned short*)d_ws;
    unsigned short* Wob  = qb  + (size_t)NTOK * E_DIM;
    unsigned short* Wqb  = Wob + (size_t)E_DIM * E_DIM;
    unsigned short* Wkb  = Wqb + (size_t)E_DIM * E_DIM;
    unsigned short* Wvb  = Wkb + (size_t)E_DIM * E_DIM;
    unsigned short* phiQ = Wvb + (size_t)E_DIM * E_DIM;
    unsigned short* phiK = phiQ + (size_t)NTOK * E_DIM;
    unsigned short* Vw   = phiK + (size_t)NTOK * E_DIM;
    float* Sp = (float*)Wqb;                          // [64][NSPLIT][64*64] f32
    float* Zp = Sp + (size_t)64 * NSPLIT * DH * DH;   // [64][NSPLIT][64] f32
    unsigned short* ctx = phiK;                       // phiK dead after kv_outer

    // 0) fp32 -> bf16
    cvt_f32_bf16<<<dim3(2048), 256, 0, stream>>>(query, qb, NTOK * E_DIM / 8);
    cvt4_f32_bf16<<<dim3(512, 1, 4), 256, 0, stream>>>(Wq, Wk, Wv, Wo,
                                                       Wqb, Wkb, Wvb, Wob,
                                                       E_DIM * E_DIM / 8);
    // 1) QKV projections (+phi on Q,K) -> bf16, XCD-swizzled 1D grid
    gemm_bt<false, 3><<<dim3(3072), 256, 0, stream>>>(qb, Wqb, Wkb, Wvb,
                                                      bq, bk, bv,
                                                      phiQ, phiK, Vw, 2);
    // 2) S^T/Z partials (Sp/Zp overwrite dead Wqb..Wvb)
    kv_outer<<<dim3(NSPLIT, 64), 256, 0, stream>>>(phiK, Vw, Sp, Zp);
    // 3) context -> bf16
    ctx_kernel<<<dim3(LSEQ / 256, 64), 256, 0, stream>>>(phiQ, Sp, Zp, ctx);
    // 4) output projection -> FP32 d_out, XCD-swizzled 1D grid
    gemm_bt<true, 1><<<dim3(1024), 256, 0, stream>>>(ctx, Wob, Wob, Wob,
                                                     bo, bo, bo,
                                                     d_out, d_out, d_out, 0);
}

// Round 7
// 293.356 us; speedup vs baseline: 1.2417x; 1.2280x over previous
//
#include <hip/hip_runtime.h>
#include <stdint.h>

// ---------------------------------------------------------------------------
// TTLinearAttention on MI355X. Inputs fp32, output fp32.
// Round 7: new 256x256 GEMM — early-issue double-buffered staging (T3-min),
// both-sides LDS XOR swizzle (T2, rule-21 compliant), setprio on MFMA (T5),
// XCD swizzle kept (T1). One barrier per K-tile.
// Pipeline (peak ws = 136 MiB):
//   0) cvt: query fp32->bf16; cvt4: weights fp32->bf16
//   1) gemm256<false,3>: phiQ/phiK/V = phi?(q @ W^T + b) -> bf16 ws
//   2) kv_outer: partial S^T/Z per (b,h,split) fp32
//   3) ctx_kernel: MFMA num+denom, ctx = num/denom -> bf16 (alias phiK)
//   4) gemm256<true,1>: out = ctx @ Wo^T + bo -> d_out fp32
// ---------------------------------------------------------------------------

typedef __attribute__((ext_vector_type(8))) short short8;
typedef __attribute__((ext_vector_type(4))) float f32x4;
typedef __attribute__((ext_vector_type(4))) unsigned short us4;
typedef __attribute__((ext_vector_type(8))) unsigned short us8;

#define E_DIM 1024
#define LSEQ 4096
#define NTOK 16384
#define DH 64
#define NSPLIT 4
#define ROWS_PER_SPLIT (LSEQ / NSPLIT) // 1024
#define BK 64

__device__ __forceinline__ float b2f(unsigned short u) {
    return __builtin_bit_cast(float, (uint32_t)u << 16);
}
__device__ __forceinline__ unsigned short f2b(float f) {
    uint32_t x = __builtin_bit_cast(uint32_t, f);
    x += 0x7FFFu + ((x >> 16) & 1u); // round-to-nearest-even
    return (unsigned short)(x >> 16);
}
__device__ __forceinline__ void gload16(const void* g, void* l) {
    __builtin_amdgcn_global_load_lds(
        (const __attribute__((address_space(1))) void*)g,
        (__attribute__((address_space(3))) void*)l, 16, 0, 0);
}

// ---------------------------------------------------------------------------
__global__ __launch_bounds__(256) void cvt_f32_bf16(
    const float* __restrict__ s, unsigned short* __restrict__ d, int n8)
{
    int i = blockIdx.x * 256 + threadIdx.x;
    const int stride = gridDim.x * 256;
    for (; i < n8; i += stride) {
        f32x4 a = ((const f32x4*)s)[(size_t)i * 2];
        f32x4 b = ((const f32x4*)s)[(size_t)i * 2 + 1];
        us8 o = { f2b(a.x), f2b(a.y), f2b(a.z), f2b(a.w),
                  f2b(b.x), f2b(b.y), f2b(b.z), f2b(b.w) };
        ((us8*)d)[i] = o;
    }
}

__global__ __launch_bounds__(256) void cvt4_f32_bf16(
    const float* __restrict__ s0, const float* __restrict__ s1,
    const float* __restrict__ s2, const float* __restrict__ s3,
    unsigned short* __restrict__ d0, unsigned short* __restrict__ d1,
    unsigned short* __restrict__ d2, unsigned short* __restrict__ d3, int n8)
{
    const int z = blockIdx.z;
    const float* s = (z == 0) ? s0 : (z == 1) ? s1 : (z == 2) ? s2 : s3;
    unsigned short* d = (z == 0) ? d0 : (z == 1) ? d1 : (z == 2) ? d2 : d3;
    int i = blockIdx.x * 256 + threadIdx.x;
    const int stride = gridDim.x * 256;
    for (; i < n8; i += stride) {
        f32x4 a = ((const f32x4*)s)[(size_t)i * 2];
        f32x4 b = ((const f32x4*)s)[(size_t)i * 2 + 1];
        us8 o = { f2b(a.x), f2b(a.y), f2b(a.z), f2b(a.w),
                  f2b(b.x), f2b(b.y), f2b(b.z), f2b(b.w) };
        ((us8*)d)[i] = o;
    }
}

// ---------------------------------------------------------------------------
// gemm256: C[m,n] = phi?( sum_k A[m,k] * W[n,k] + bias[n] )   (bias fp32)
// BM=BN=256, BK=64; 512 threads = 8 waves (2M x 4N), wave tile 128x64.
// LDS: 2-buf x (A 32K + B 32K) = 128 KiB. Per K-tile: STAGE(next) issued at
// top, 24 swizzled ds_read_b128 + 64 MFMA, ONE __syncthreads (vmcnt drain
// hidden under compute). LDS swizzle: 16B-chunk ^= (row&7) — inverse-applied
// on the global source (stage), forward-applied on ds_read.
// Grid 1D, XCD-swizzled: xcd=bid%8 owns contiguous (mt,(nt,z)) chunk.
// ---------------------------------------------------------------------------
template <bool OUTF32, int NZ>
__global__ __launch_bounds__(512, 2) void gemm256(
    const unsigned short* __restrict__ A,
    const unsigned short* __restrict__ W0, const unsigned short* __restrict__ W1,
    const unsigned short* __restrict__ W2,
    const float* __restrict__ b0, const float* __restrict__ b1,
    const float* __restrict__ b2,
    void* __restrict__ o0, void* __restrict__ o1, void* __restrict__ o2,
    int nphi)
{
    __shared__ unsigned short As[2][256 * BK];
    __shared__ unsigned short Bs[2][256 * BK];

    // --- T1 XCD swizzle (bijective: nwg = 64*4*NZ, divisible by 8) ---
    const int bid   = blockIdx.x;
    const int chunk = (64 * 4 * NZ) / 8;
    const int swz   = (bid & 7) * chunk + (bid >> 3);
    const int mt    = swz / (4 * NZ);
    const int rem   = swz % (4 * NZ);
    const int nt    = rem & 3;
    const int z     = rem >> 2;

    const unsigned short* W = (z == 0) ? W0 : ((z == 1) ? W1 : W2);
    const float* bias       = (z == 0) ? b0 : ((z == 1) ? b1 : b2);
    void* out               = (z == 0) ? o0 : ((z == 1) ? o1 : o2);
    const bool phi = z < nphi;

    const int tid  = threadIdx.x;
    const int lane = tid & 63;
    const int w    = tid >> 6;      // wave 0..7
    const int wr   = w >> 2;        // 0..1  (m half)
    const int wc   = w & 3;         // 0..3  (n quarter)
    const int m0   = mt * 256;
    const int n0   = nt * 256;

    // staging geometry: wave w covers rows c*64 + w*8 .. +7 per call, c=0..3
    const int r8  = lane >> 3;                    // 0..7 (row within 8-stripe)
    const int csw = ((lane & 7) ^ r8) * 8;        // inverse-swizzled k-chunk

    f32x4 acc[8][4] = {};

    // prologue: stage K-tile 0 into buf 0
    {
#pragma unroll
        for (int c = 0; c < 4; ++c) {
            const int rr = c * 64 + w * 8;
            gload16(&A[(size_t)(m0 + rr + r8) * E_DIM + csw], &As[0][rr * BK]);
            gload16(&W[(size_t)(n0 + rr + r8) * E_DIM + csw], &Bs[0][rr * BK]);
        }
    }
    __syncthreads();

    for (int kt = 0; kt < E_DIM / BK; ++kt) {
        const int cur = kt & 1;
        // early-issue next K-tile into the other buffer (hidden under MFMA)
        if (kt + 1 < E_DIM / BK) {
            const int k0 = (kt + 1) * BK;
#pragma unroll
            for (int c = 0; c < 4; ++c) {
                const int rr = c * 64 + w * 8;
                gload16(&A[(size_t)(m0 + rr + r8) * E_DIM + k0 + csw],
                        &As[cur ^ 1][rr * BK]);
                gload16(&W[(size_t)(n0 + rr + r8) * E_DIM + k0 + csw],
                        &Bs[cur ^ 1][rr * BK]);
            }
        }
        // compute current K-tile
#pragma unroll
        for (int kk = 0; kk < 2; ++kk) {
            const int rsel = lane & 15;
            const int kx = ((kk * 4 + (lane >> 4)) ^ (lane & 7)) * 8; // swizzled read
            short8 af[8], bf[4];
#pragma unroll
            for (int mi = 0; mi < 8; ++mi)
                af[mi] = *(const short8*)&As[cur][(wr * 128 + mi * 16 + rsel) * BK + kx];
#pragma unroll
            for (int ni = 0; ni < 4; ++ni)
                bf[ni] = *(const short8*)&Bs[cur][(wc * 64 + ni * 16 + rsel) * BK + kx];
            __builtin_amdgcn_s_setprio(1);
#pragma unroll
            for (int mi = 0; mi < 8; ++mi)
#pragma unroll
                for (int ni = 0; ni < 4; ++ni)
                    acc[mi][ni] = __builtin_amdgcn_mfma_f32_16x16x32_bf16(
                        af[mi], bf[ni], acc[mi][ni], 0, 0, 0);
            __builtin_amdgcn_s_setprio(0);
        }
        __syncthreads(); // drains next-tile loads (issued ~1000cy ago) + lgkm
    }

    // epilogue: C/D layout col=lane&15, row=(lane>>4)*4+r
#pragma unroll
    for (int mi = 0; mi < 8; ++mi) {
        const int rbase = m0 + wr * 128 + mi * 16 + ((lane >> 4) << 2);
#pragma unroll
        for (int ni = 0; ni < 4; ++ni) {
            const int col = n0 + wc * 64 + ni * 16 + (lane & 15);
            const float bv = bias[col];
#pragma unroll
            for (int r = 0; r < 4; ++r) {
                float v = acc[mi][ni][r] + bv;
                if (phi) v = (v > 0.f) ? (v + 1.f) : __expf(v); // elu(v)+1
                if (OUTF32)
                    ((float*)out)[(size_t)(rbase + r) * E_DIM + col] = v;
                else
                    ((unsigned short*)out)[(size_t)(rbase + r) * E_DIM + col] = f2b(v);
            }
        }
    }
}

// ---------------------------------------------------------------------------
// kv_outer: per (b,h,split) partial S^T[j][i] = sum_l phiK[l,i]*V[l,j], Z[i].
// ---------------------------------------------------------------------------
__global__ __launch_bounds__(256) void kv_outer(
    const unsigned short* __restrict__ K, const unsigned short* __restrict__ V,
    float* __restrict__ Sp, float* __restrict__ Zp)
{
    __shared__ float kb[8][64];
    __shared__ float vb[8][64];
    const int split = blockIdx.x;
    const int bh    = blockIdx.y;
    const int b = bh >> 4, h = bh & 15;
    const int t  = threadIdx.x;
    const int i0 = (t & 15) * 4;
    const int j0 = (t >> 4) * 4;
    const int sr = t >> 5;
    const int sc = (t & 31) * 4;

    const unsigned short* sbase = (sc < 64) ? K : V;
    size_t gbase = ((size_t)(b * LSEQ + split * ROWS_PER_SPLIT)) * E_DIM + h * DH;

    f32x4 acc[4] = {};
    f32x4 zacc = {};

    for (int chunk = 0; chunk < ROWS_PER_SPLIT / 8; ++chunk) {
        us4 u = *(const us4*)&sbase[gbase + (size_t)sr * E_DIM + (sc & 63)];
        f32x4 fv = { b2f(u.x), b2f(u.y), b2f(u.z), b2f(u.w) };
        float* dst = (sc < 64) ? &kb[sr][sc] : &vb[sr][sc - 64];
        *(f32x4*)dst = fv;
        __syncthreads();
#pragma unroll
        for (int rr = 0; rr < 8; ++rr) {
            f32x4 kv = *(const f32x4*)&kb[rr][i0];
            f32x4 vv = *(const f32x4*)&vb[rr][j0];
            acc[0] += kv * vv.x;
            acc[1] += kv * vv.y;
            acc[2] += kv * vv.z;
            acc[3] += kv * vv.w;
            if ((t >> 4) == 0) zacc += kv;
        }
        __syncthreads();
        gbase += (size_t)8 * E_DIM;
    }

    const size_t sb = ((size_t)bh * NSPLIT + split) * (DH * DH);
#pragma unroll
    for (int jj = 0; jj < 4; ++jj)
        *(f32x4*)&Sp[sb + (size_t)(j0 + jj) * DH + i0] = acc[jj];
    if ((t >> 4) == 0)
        *(f32x4*)&Zp[((size_t)bh * NSPLIT + split) * DH + i0] = zacc;
}

// ---------------------------------------------------------------------------
// ctx_kernel: per (b,h): B-tile = [S^T (64 rows) | Z (row 64) | zeros]
// bf16 in LDS. num+denom via MFMA (5 n-frags); ctx = num/(denom+eps).
// ---------------------------------------------------------------------------
__global__ __launch_bounds__(256) void ctx_kernel(
    const unsigned short* __restrict__ Q, const float* __restrict__ Sp,
    const float* __restrict__ Zp, unsigned short* __restrict__ ctx)
{
    __shared__ unsigned short Bs[80 * 64];
    const int bh = blockIdx.y;
    const int b = bh >> 4, h = bh & 15;
    const int t    = threadIdx.x;
    const int lane = t & 63;
    const int w    = t >> 6;

    for (int e = t; e < 4096; e += 256) {
        float s = 0.f;
#pragma unroll
        for (int p = 0; p < NSPLIT; ++p)
            s += Sp[((size_t)bh * NSPLIT + p) * (DH * DH) + e];
        Bs[e] = f2b(s);
    }
    if (t < 64) {
        float zv = 0.f;
#pragma unroll
        for (int p = 0; p < NSPLIT; ++p)
            zv += Zp[((size_t)bh * NSPLIT + p) * DH + t];
        Bs[64 * 64 + t] = f2b(zv);
    }
    for (int e = t; e < 15 * 64; e += 256) Bs[65 * 64 + e] = 0;
    __syncthreads();

    const int m0 = blockIdx.x * 256 + w * 64;
    f32x4 acc[4][5] = {};
#pragma unroll
    for (int kk = 0; kk < 2; ++kk) {
        const int krd = kk * 32 + (lane >> 4) * 8;
        short8 af[4];
#pragma unroll
        for (int mi = 0; mi < 4; ++mi) {
            const int l = m0 + mi * 16 + (lane & 15);
            af[mi] = *(const short8*)&Q[((size_t)(b * LSEQ + l)) * E_DIM + h * DH + krd];
        }
#pragma unroll
        for (int ni = 0; ni < 5; ++ni) {
            short8 bfr = *(const short8*)&Bs[(ni * 16 + (lane & 15)) * 64 + krd];
#pragma unroll
            for (int mi = 0; mi < 4; ++mi)
                acc[mi][ni] = __builtin_amdgcn_mfma_f32_16x16x32_bf16(
                    af[mi], bfr, acc[mi][ni], 0, 0, 0);
        }
    }
#pragma unroll
    for (int mi = 0; mi < 4; ++mi) {
#pragma unroll
        for (int r = 0; r < 4; ++r) {
            const float dv  = __shfl(acc[mi][4][r], lane & 48, 64); // denom (col 64)
            const float inv = 1.f / (dv + 1e-6f);
            const int l = m0 + mi * 16 + ((lane >> 4) << 2) + r;
#pragma unroll
            for (int ni = 0; ni < 4; ++ni)
                ctx[((size_t)(b * LSEQ + l)) * E_DIM + h * DH + ni * 16 + (lane & 15)] =
                    f2b(acc[mi][ni][r] * inv);
        }
    }
}

// ---------------------------------------------------------------------------
extern "C" void kernel_launch(void* const* d_in, const int* in_sizes, int n_in,
                              void* d_out, int out_size, void* d_ws, size_t ws_size,
                              hipStream_t stream)
{
    const float* query = (const float*)d_in[0];
    const float* Wq = (const float*)d_in[1];
    const float* bq = (const float*)d_in[2];
    const float* Wk = (const float*)d_in[3];
    const float* bk = (const float*)d_in[4];
    const float* Wv = (const float*)d_in[5];
    const float* bv = (const float*)d_in[6];
    const float* Wo = (const float*)d_in[7];
    const float* bo = (const float*)d_in[8];

    // ws (136 MiB peak):
    //   [qb 32MiB | Wob 2 | Wqb 2 | Wkb 2 | Wvb 2 | phiQ 32 | phiK 32 | Vw 32]
    //   Sp/Zp (4.07 MiB) alias Wqb..Wvb after gemm1; ctx aliases phiK.
    unsigned short* qb   = (unsigned short*)d_ws;
    unsigned short* Wob  = qb  + (size_t)NTOK * E_DIM;
    unsigned short* Wqb  = Wob + (size_t)E_DIM * E_DIM;
    unsigned short* Wkb  = Wqb + (size_t)E_DIM * E_DIM;
    unsigned short* Wvb  = Wkb + (size_t)E_DIM * E_DIM;
    unsigned short* phiQ = Wvb + (size_t)E_DIM * E_DIM;
    unsigned short* phiK = phiQ + (size_t)NTOK * E_DIM;
    unsigned short* Vw   = phiK + (size_t)NTOK * E_DIM;
    float* Sp = (float*)Wqb;                          // [64][NSPLIT][64*64] f32
    float* Zp = Sp + (size_t)64 * NSPLIT * DH * DH;   // [64][NSPLIT][64] f32
    unsigned short* ctx = phiK;                       // phiK dead after kv_outer

    // 0) fp32 -> bf16
    cvt_f32_bf16<<<dim3(2048), 256, 0, stream>>>(query, qb, NTOK * E_DIM / 8);
    cvt4_f32_bf16<<<dim3(512, 1, 4), 256, 0, stream>>>(Wq, Wk, Wv, Wo,
                                                       Wqb, Wkb, Wvb, Wob,
                                                       E_DIM * E_DIM / 8);
    // 1) QKV projections (+phi on Q,K) -> bf16; 64 m-tiles x 4 n-tiles x 3
    gemm256<false, 3><<<dim3(768), 512, 0, stream>>>(qb, Wqb, Wkb, Wvb,
                                                     bq, bk, bv,
                                                     phiQ, phiK, Vw, 2);
    // 2) S^T/Z partials (Sp/Zp overwrite dead Wqb..Wvb)
    kv_outer<<<dim3(NSPLIT, 64), 256, 0, stream>>>(phiK, Vw, Sp, Zp);
    // 3) context -> bf16
    ctx_kernel<<<dim3(LSEQ / 256, 64), 256, 0, stream>>>(phiQ, Sp, Zp, ctx);
    // 4) output projection -> FP32 d_out; 64 x 4 tiles
    gemm256<true, 1><<<dim3(256), 512, 0, stream>>>(ctx, Wob, Wob, Wob,
                                                    bo, bo, bo,
                                                    d_out, d_out, d_out, 0);
}

// Round 8
// 273.710 us; speedup vs baseline: 1.3308x; 1.0718x over previous
//
#include <hip/hip_runtime.h>
#include <stdint.h>

// ---------------------------------------------------------------------------
// TTLinearAttention on MI355X. Inputs fp32, output fp32.
// Round 8: GEMM K-loop -> 3-deep pipeline, BK=32, counted s_waitcnt vmcnt(4)
// + raw s_barrier (loads bridge barriers, T4). LDS 96KB. Swizzle key (row>>1)&3
// on 16B chunks (2-way = free). kv_outer NSPLIT 16 (Sp aliases dead qb).
// Pipeline (peak ws = 136 MiB):
//   0) cvt: query fp32->bf16; cvt4: weights fp32->bf16
//   1) gemm256<false,3>: phiQ/phiK/V = phi?(q @ W^T + b) -> bf16 ws
//   2) kv_outer: partial S^T/Z per (b,h,split) fp32
//   3) ctx_kernel: MFMA num+denom, ctx = num/denom -> bf16 (alias phiK)
//   4) gemm256<true,1>: out = ctx @ Wo^T + bo -> d_out fp32
// ---------------------------------------------------------------------------

typedef __attribute__((ext_vector_type(8))) short short8;
typedef __attribute__((ext_vector_type(4))) float f32x4;
typedef __attribute__((ext_vector_type(4))) unsigned short us4;
typedef __attribute__((ext_vector_type(8))) unsigned short us8;

#define E_DIM 1024
#define LSEQ 4096
#define NTOK 16384
#define DH 64
#define NSPLIT 16
#define ROWS_PER_SPLIT (LSEQ / NSPLIT) // 256
#define BKT 32
#define NT (E_DIM / BKT) // 32 K-tiles

__device__ __forceinline__ float b2f(unsigned short u) {
    return __builtin_bit_cast(float, (uint32_t)u << 16);
}
__device__ __forceinline__ unsigned short f2b(float f) {
    uint32_t x = __builtin_bit_cast(uint32_t, f);
    x += 0x7FFFu + ((x >> 16) & 1u); // round-to-nearest-even
    return (unsigned short)(x >> 16);
}
__device__ __forceinline__ void gload16(const void* g, void* l) {
    __builtin_amdgcn_global_load_lds(
        (const __attribute__((address_space(1))) void*)g,
        (__attribute__((address_space(3))) void*)l, 16, 0, 0);
}

// ---------------------------------------------------------------------------
__global__ __launch_bounds__(256) void cvt_f32_bf16(
    const float* __restrict__ s, unsigned short* __restrict__ d, int n8)
{
    int i = blockIdx.x * 256 + threadIdx.x;
    const int stride = gridDim.x * 256;
    for (; i < n8; i += stride) {
        f32x4 a = ((const f32x4*)s)[(size_t)i * 2];
        f32x4 b = ((const f32x4*)s)[(size_t)i * 2 + 1];
        us8 o = { f2b(a.x), f2b(a.y), f2b(a.z), f2b(a.w),
                  f2b(b.x), f2b(b.y), f2b(b.z), f2b(b.w) };
        ((us8*)d)[i] = o;
    }
}

__global__ __launch_bounds__(256) void cvt4_f32_bf16(
    const float* __restrict__ s0, const float* __restrict__ s1,
    const float* __restrict__ s2, const float* __restrict__ s3,
    unsigned short* __restrict__ d0, unsigned short* __restrict__ d1,
    unsigned short* __restrict__ d2, unsigned short* __restrict__ d3, int n8)
{
    const int z = blockIdx.z;
    const float* s = (z == 0) ? s0 : (z == 1) ? s1 : (z == 2) ? s2 : s3;
    unsigned short* d = (z == 0) ? d0 : (z == 1) ? d1 : (z == 2) ? d2 : d3;
    int i = blockIdx.x * 256 + threadIdx.x;
    const int stride = gridDim.x * 256;
    for (; i < n8; i += stride) {
        f32x4 a = ((const f32x4*)s)[(size_t)i * 2];
        f32x4 b = ((const f32x4*)s)[(size_t)i * 2 + 1];
        us8 o = { f2b(a.x), f2b(a.y), f2b(a.z), f2b(a.w),
                  f2b(b.x), f2b(b.y), f2b(b.z), f2b(b.w) };
        ((us8*)d)[i] = o;
    }
}

// ---------------------------------------------------------------------------
// gemm256: C[m,n] = phi?( sum_k A[m,k] * W[n,k] + bias[n] )   (bias fp32)
// BM=BN=256, BKT=32; 512 threads = 8 waves (2M x 4N), wave tile 128x64.
// LDS: 3 bufs x (A 16K + B 16K) = 96 KiB. Per K-tile kt:
//   s_waitcnt vmcnt(4); s_barrier;      // tile kt landed, kt+1 stays in flight
//   STAGE(kt+2);                        // 4 gload_lds calls/wave
//   12 swizzled ds_read_b128; 32 MFMA (setprio).
// Swizzle: LDS[r][chunk] holds global chunk^((r>>1)&3) (16B chunks, 4/row);
// source pre-swizzle (lane&3)^((lane>>3)&3); read chunk c -> c^((r>>1)&3).
// Grid 1D, XCD-swizzled (bijective, nwg%8==0).
// ---------------------------------------------------------------------------
template <bool OUTF32, int NZ>
__global__ __launch_bounds__(512, 2) void gemm256(
    const unsigned short* __restrict__ A,
    const unsigned short* __restrict__ W0, const unsigned short* __restrict__ W1,
    const unsigned short* __restrict__ W2,
    const float* __restrict__ b0, const float* __restrict__ b1,
    const float* __restrict__ b2,
    void* __restrict__ o0, void* __restrict__ o1, void* __restrict__ o2,
    int nphi)
{
    __shared__ unsigned short As[3][256 * BKT];
    __shared__ unsigned short Bs[3][256 * BKT];

    // --- T1 XCD swizzle (bijective: nwg = 64*4*NZ, divisible by 8) ---
    const int bid   = blockIdx.x;
    const int chunk = (64 * 4 * NZ) / 8;
    const int swz   = (bid & 7) * chunk + (bid >> 3);
    const int mt    = swz / (4 * NZ);
    const int rem   = swz % (4 * NZ);
    const int nt    = rem & 3;
    const int z     = rem >> 2;

    const unsigned short* W = (z == 0) ? W0 : ((z == 1) ? W1 : W2);
    const float* bias       = (z == 0) ? b0 : ((z == 1) ? b1 : b2);
    void* out               = (z == 0) ? o0 : ((z == 1) ? o1 : o2);
    const bool phi = z < nphi;

    const int tid  = threadIdx.x;
    const int lane = tid & 63;
    const int w    = tid >> 6;      // wave 0..7
    const int wr   = w >> 2;        // 0..1  (m half)
    const int wc   = w & 3;         // 0..3  (n quarter)
    const int m0   = mt * 256;
    const int n0   = nt * 256;

    // staging geometry: per call, wave w writes rows base+sq (sq=lane>>2),
    // LDS chunk lane&3; global source chunk pre-swizzled.
    const int sq   = lane >> 2;                          // 0..15
    const int schk = ((lane & 3) ^ ((lane >> 3) & 3)) * 8; // elems

    f32x4 acc[8][4] = {};

#define STAGE(KT, BUF)                                                         \
    {                                                                          \
        const int k0_ = (KT) * BKT;                                            \
        _Pragma("unroll")                                                      \
        for (int c = 0; c < 2; ++c) {                                          \
            const int rr = c * 128 + w * 16;                                   \
            gload16(&A[(size_t)(m0 + rr + sq) * E_DIM + k0_ + schk],           \
                    &As[BUF][rr * BKT]);                                       \
            gload16(&W[(size_t)(n0 + rr + sq) * E_DIM + k0_ + schk],           \
                    &Bs[BUF][rr * BKT]);                                       \
        }                                                                      \
    }

    // prologue: tiles 0,1 in flight (8 vmem ops/wave)
    STAGE(0, 0);
    STAGE(1, 1);

    int cur = 0;
    for (int kt = 0; kt < NT; ++kt) {
        // tile kt complete; tile kt+1's 4 loads stay in flight (T4)
        if (kt < NT - 1)
            asm volatile("s_waitcnt vmcnt(4)" ::: "memory");
        else
            asm volatile("s_waitcnt vmcnt(0)" ::: "memory");
        __builtin_amdgcn_s_barrier();
        if (kt + 2 < NT) {
            int nb = cur + 2; if (nb >= 3) nb -= 3;
            STAGE(kt + 2, nb);
        }
        const int rsel = lane & 15;
        const int kx   = (((lane >> 4) ^ ((rsel >> 1) & 3))) * 8; // swizzled read
        short8 af[8], bf[4];
#pragma unroll
        for (int mi = 0; mi < 8; ++mi)
            af[mi] = *(const short8*)&As[cur][(wr * 128 + mi * 16 + rsel) * BKT + kx];
#pragma unroll
        for (int ni = 0; ni < 4; ++ni)
            bf[ni] = *(const short8*)&Bs[cur][(wc * 64 + ni * 16 + rsel) * BKT + kx];
        __builtin_amdgcn_s_setprio(1);
#pragma unroll
        for (int mi = 0; mi < 8; ++mi)
#pragma unroll
            for (int ni = 0; ni < 4; ++ni)
                acc[mi][ni] = __builtin_amdgcn_mfma_f32_16x16x32_bf16(
                    af[mi], bf[ni], acc[mi][ni], 0, 0, 0);
        __builtin_amdgcn_s_setprio(0);
        ++cur; if (cur == 3) cur = 0;
    }
#undef STAGE

    // epilogue: C/D layout col=lane&15, row=(lane>>4)*4+r
#pragma unroll
    for (int mi = 0; mi < 8; ++mi) {
        const int rbase = m0 + wr * 128 + mi * 16 + ((lane >> 4) << 2);
#pragma unroll
        for (int ni = 0; ni < 4; ++ni) {
            const int col = n0 + wc * 64 + ni * 16 + (lane & 15);
            const float bv = bias[col];
#pragma unroll
            for (int r = 0; r < 4; ++r) {
                float v = acc[mi][ni][r] + bv;
                if (phi) v = (v > 0.f) ? (v + 1.f) : __expf(v); // elu(v)+1
                if (OUTF32)
                    ((float*)out)[(size_t)(rbase + r) * E_DIM + col] = v;
                else
                    ((unsigned short*)out)[(size_t)(rbase + r) * E_DIM + col] = f2b(v);
            }
        }
    }
}

// ---------------------------------------------------------------------------
// kv_outer: per (b,h,split) partial S^T[j][i] = sum_l phiK[l,i]*V[l,j], Z[i].
// ---------------------------------------------------------------------------
__global__ __launch_bounds__(256) void kv_outer(
    const unsigned short* __restrict__ K, const unsigned short* __restrict__ V,
    float* __restrict__ Sp, float* __restrict__ Zp)
{
    __shared__ float kb[8][64];
    __shared__ float vb[8][64];
    const int split = blockIdx.x;
    const int bh    = blockIdx.y;
    const int b = bh >> 4, h = bh & 15;
    const int t  = threadIdx.x;
    const int i0 = (t & 15) * 4;
    const int j0 = (t >> 4) * 4;
    const int sr = t >> 5;
    const int sc = (t & 31) * 4;

    const unsigned short* sbase = (sc < 64) ? K : V;
    size_t gbase = ((size_t)(b * LSEQ + split * ROWS_PER_SPLIT)) * E_DIM + h * DH;

    f32x4 acc[4] = {};
    f32x4 zacc = {};

    for (int chunk = 0; chunk < ROWS_PER_SPLIT / 8; ++chunk) {
        us4 u = *(const us4*)&sbase[gbase + (size_t)sr * E_DIM + (sc & 63)];
        f32x4 fv = { b2f(u.x), b2f(u.y), b2f(u.z), b2f(u.w) };
        float* dst = (sc < 64) ? &kb[sr][sc] : &vb[sr][sc - 64];
        *(f32x4*)dst = fv;
        __syncthreads();
#pragma unroll
        for (int rr = 0; rr < 8; ++rr) {
            f32x4 kv = *(const f32x4*)&kb[rr][i0];
            f32x4 vv = *(const f32x4*)&vb[rr][j0];
            acc[0] += kv * vv.x;
            acc[1] += kv * vv.y;
            acc[2] += kv * vv.z;
            acc[3] += kv * vv.w;
            if ((t >> 4) == 0) zacc += kv;
        }
        __syncthreads();
        gbase += (size_t)8 * E_DIM;
    }

    const size_t sb = ((size_t)bh * NSPLIT + split) * (DH * DH);
#pragma unroll
    for (int jj = 0; jj < 4; ++jj)
        *(f32x4*)&Sp[sb + (size_t)(j0 + jj) * DH + i0] = acc[jj];
    if ((t >> 4) == 0)
        *(f32x4*)&Zp[((size_t)bh * NSPLIT + split) * DH + i0] = zacc;
}

// ---------------------------------------------------------------------------
// ctx_kernel: per (b,h): B-tile = [S^T (64 rows) | Z (row 64) | zeros]
// bf16 in LDS. num+denom via MFMA (5 n-frags); ctx = num/(denom+eps).
// ---------------------------------------------------------------------------
__global__ __launch_bounds__(256) void ctx_kernel(
    const unsigned short* __restrict__ Q, const float* __restrict__ Sp,
    const float* __restrict__ Zp, unsigned short* __restrict__ ctx)
{
    __shared__ unsigned short Bs[80 * 64];
    const int bh = blockIdx.y;
    const int b = bh >> 4, h = bh & 15;
    const int t    = threadIdx.x;
    const int lane = t & 63;
    const int w    = t >> 6;

    for (int e = t; e < 4096; e += 256) {
        float s = 0.f;
#pragma unroll
        for (int p = 0; p < NSPLIT; ++p)
            s += Sp[((size_t)bh * NSPLIT + p) * (DH * DH) + e];
        Bs[e] = f2b(s);
    }
    if (t < 64) {
        float zv = 0.f;
#pragma unroll
        for (int p = 0; p < NSPLIT; ++p)
            zv += Zp[((size_t)bh * NSPLIT + p) * DH + t];
        Bs[64 * 64 + t] = f2b(zv);
    }
    for (int e = t; e < 15 * 64; e += 256) Bs[65 * 64 + e] = 0;
    __syncthreads();

    const int m0 = blockIdx.x * 256 + w * 64;
    f32x4 acc[4][5] = {};
#pragma unroll
    for (int kk = 0; kk < 2; ++kk) {
        const int krd = kk * 32 + (lane >> 4) * 8;
        short8 af[4];
#pragma unroll
        for (int mi = 0; mi < 4; ++mi) {
            const int l = m0 + mi * 16 + (lane & 15);
            af[mi] = *(const short8*)&Q[((size_t)(b * LSEQ + l)) * E_DIM + h * DH + krd];
        }
#pragma unroll
        for (int ni = 0; ni < 5; ++ni) {
            short8 bfr = *(const short8*)&Bs[(ni * 16 + (lane & 15)) * 64 + krd];
#pragma unroll
            for (int mi = 0; mi < 4; ++mi)
                acc[mi][ni] = __builtin_amdgcn_mfma_f32_16x16x32_bf16(
                    af[mi], bfr, acc[mi][ni], 0, 0, 0);
        }
    }
#pragma unroll
    for (int mi = 0; mi < 4; ++mi) {
#pragma unroll
        for (int r = 0; r < 4; ++r) {
            const float dv  = __shfl(acc[mi][4][r], lane & 48, 64); // denom (col 64)
            const float inv = 1.f / (dv + 1e-6f);
            const int l = m0 + mi * 16 + ((lane >> 4) << 2) + r;
#pragma unroll
            for (int ni = 0; ni < 4; ++ni)
                ctx[((size_t)(b * LSEQ + l)) * E_DIM + h * DH + ni * 16 + (lane & 15)] =
                    f2b(acc[mi][ni][r] * inv);
        }
    }
}

// ---------------------------------------------------------------------------
extern "C" void kernel_launch(void* const* d_in, const int* in_sizes, int n_in,
                              void* d_out, int out_size, void* d_ws, size_t ws_size,
                              hipStream_t stream)
{
    const float* query = (const float*)d_in[0];
    const float* Wq = (const float*)d_in[1];
    const float* bq = (const float*)d_in[2];
    const float* Wk = (const float*)d_in[3];
    const float* bk = (const float*)d_in[4];
    const float* Wv = (const float*)d_in[5];
    const float* bv = (const float*)d_in[6];
    const float* Wo = (const float*)d_in[7];
    const float* bo = (const float*)d_in[8];

    // ws (136 MiB peak):
    //   [qb 32MiB | Wob 2 | Wqb 2 | Wkb 2 | Wvb 2 | phiQ 32 | phiK 32 | Vw 32]
    //   Sp/Zp (16.25 MiB) alias qb after gemm1; ctx aliases phiK.
    unsigned short* qb   = (unsigned short*)d_ws;
    unsigned short* Wob  = qb  + (size_t)NTOK * E_DIM;
    unsigned short* Wqb  = Wob + (size_t)E_DIM * E_DIM;
    unsigned short* Wkb  = Wqb + (size_t)E_DIM * E_DIM;
    unsigned short* Wvb  = Wkb + (size_t)E_DIM * E_DIM;
    unsigned short* phiQ = Wvb + (size_t)E_DIM * E_DIM;
    unsigned short* phiK = phiQ + (size_t)NTOK * E_DIM;
    unsigned short* Vw   = phiK + (size_t)NTOK * E_DIM;
    float* Sp = (float*)qb;                           // [64][NSPLIT][64*64] f32
    float* Zp = Sp + (size_t)64 * NSPLIT * DH * DH;   // [64][NSPLIT][64] f32
    unsigned short* ctx = phiK;                       // phiK dead after kv_outer

    // 0) fp32 -> bf16
    cvt_f32_bf16<<<dim3(2048), 256, 0, stream>>>(query, qb, NTOK * E_DIM / 8);
    cvt4_f32_bf16<<<dim3(512, 1, 4), 256, 0, stream>>>(Wq, Wk, Wv, Wo,
                                                       Wqb, Wkb, Wvb, Wob,
                                                       E_DIM * E_DIM / 8);
    // 1) QKV projections (+phi on Q,K) -> bf16; 64 m-tiles x 4 n-tiles x 3
    gemm256<false, 3><<<dim3(768), 512, 0, stream>>>(qb, Wqb, Wkb, Wvb,
                                                     bq, bk, bv,
                                                     phiQ, phiK, Vw, 2);
    // 2) S^T/Z partials (Sp/Zp overwrite dead qb)
    kv_outer<<<dim3(NSPLIT, 64), 256, 0, stream>>>(phiK, Vw, Sp, Zp);
    // 3) context -> bf16
    ctx_kernel<<<dim3(LSEQ / 256, 64), 256, 0, stream>>>(phiQ, Sp, Zp, ctx);
    // 4) output projection -> FP32 d_out; 64 x 4 tiles
    gemm256<true, 1><<<dim3(256), 512, 0, stream>>>(ctx, Wob, Wob, Wob,
                                                    bo, bo, bo,
                                                    d_out, d_out, d_out, 0);
}

// Round 10
// 247.081 us; speedup vs baseline: 1.4743x; 1.1078x over previous
//
#include <hip/hip_runtime.h>
#include <stdint.h>

// ---------------------------------------------------------------------------
// TTLinearAttention on MI355X. Inputs fp32, output fp32.
// Round 10: GEMM back to the PROVEN m97 2-barrier structure at 128x128 tile,
// 32KB LDS, launch_bounds(256,4) -> ~5 blocks/CU: cross-block overlap (m114)
// hides the stage drain that 1-block/CU 256^2 schedules stall on. T2 swizzle
// (R7's verified maps) + T1 XCD decode (R6). NSPLIT=16 kv_outer. cvt merged.
// NOTE (R9 lesson): custom counted-vmcnt schedules race across graph replays;
// this kernel uses only __syncthreads() between stage and read - proven safe.
// ---------------------------------------------------------------------------

typedef __attribute__((ext_vector_type(8))) short short8;
typedef __attribute__((ext_vector_type(4))) float f32x4;
typedef __attribute__((ext_vector_type(4))) unsigned short us4;
typedef __attribute__((ext_vector_type(8))) unsigned short us8;

#define E_DIM 1024
#define LSEQ 4096
#define NTOK 16384
#define DH 64
#define NSPLIT 16
#define ROWS_PER_SPLIT (LSEQ / NSPLIT) // 256

__device__ __forceinline__ float b2f(unsigned short u) {
    return __builtin_bit_cast(float, (uint32_t)u << 16);
}
__device__ __forceinline__ unsigned short f2b(float f) {
    uint32_t x = __builtin_bit_cast(uint32_t, f);
    x += 0x7FFFu + ((x >> 16) & 1u); // round-to-nearest-even
    return (unsigned short)(x >> 16);
}
__device__ __forceinline__ void gload16(const void* g, void* l) {
    __builtin_amdgcn_global_load_lds(
        (const __attribute__((address_space(1))) void*)g,
        (__attribute__((address_space(3))) void*)l, 16, 0, 0);
}

// ---------------------------------------------------------------------------
// cvt_all: one dispatch converts query (blocks 0..2047) and the 4 weight
// matrices (128 blocks each). Every thread: 4 x us8 groups (8192 B/block).
// ---------------------------------------------------------------------------
__global__ __launch_bounds__(256) void cvt_all(
    const float* __restrict__ q,
    const float* __restrict__ w0, const float* __restrict__ w1,
    const float* __restrict__ w2, const float* __restrict__ w3,
    unsigned short* __restrict__ dq,
    unsigned short* __restrict__ d0, unsigned short* __restrict__ d1,
    unsigned short* __restrict__ d2, unsigned short* __restrict__ d3)
{
    const int bid = blockIdx.x;
    const float* s;
    unsigned short* d;
    int base;
    if (bid < 2048) {
        s = q; d = dq; base = bid * 1024;
    } else {
        const int k = (bid - 2048) >> 7;
        s = (k == 0) ? w0 : (k == 1) ? w1 : (k == 2) ? w2 : w3;
        d = (k == 0) ? d0 : (k == 1) ? d1 : (k == 2) ? d2 : d3;
        base = ((bid - 2048) & 127) * 1024;
    }
#pragma unroll
    for (int j = 0; j < 4; ++j) {
        const int i = base + j * 256 + threadIdx.x;
        f32x4 a = ((const f32x4*)s)[(size_t)i * 2];
        f32x4 b = ((const f32x4*)s)[(size_t)i * 2 + 1];
        us8 o = { f2b(a.x), f2b(a.y), f2b(a.z), f2b(a.w),
                  f2b(b.x), f2b(b.y), f2b(b.z), f2b(b.w) };
        ((us8*)d)[i] = o;
    }
}

// ---------------------------------------------------------------------------
// gemm128: C[m,n] = phi?( sum_k A[m,k] * W[n,k] + bias[n] )   (bias fp32)
// m97 structure: 128x128 tile, BK=64, 256 threads = 4 waves (2x2), wave tile
// 64x64. LDS 32KB single-buffer; per K-tile: stage (8 gload16) -> sync ->
// 16 swizzled ds_read_b128 + 32 MFMA -> sync. ~5 blocks/CU hide the drain.
// T2 swizzle: LDS[row][chunk]=global[row][chunk^(row&7)] (16B chunks);
// stage pre-swizzles source (lane&7)^(lane>>3); read XORs chunk with lane&7.
// Grid 1D XCD-swizzled: m slowest, (n,z) fastest (R6 decode).
// ---------------------------------------------------------------------------
template <bool OUTF32, int NZ>
__global__ __launch_bounds__(256, 4) void gemm128(
    const unsigned short* __restrict__ A,
    const unsigned short* __restrict__ W0, const unsigned short* __restrict__ W1,
    const unsigned short* __restrict__ W2,
    const float* __restrict__ b0, const float* __restrict__ b1,
    const float* __restrict__ b2,
    void* __restrict__ o0, void* __restrict__ o1, void* __restrict__ o2,
    int nphi)
{
    __shared__ unsigned short As[128 * 64];
    __shared__ unsigned short Bs[128 * 64];

    // --- T1 XCD swizzle (bijective: nwg = 128*8*NZ, divisible by 8) ---
    const int bid   = blockIdx.x;
    const int chunk = (128 * 8 * NZ) / 8;
    const int swz   = (bid & 7) * chunk + (bid >> 3);
    const int mt    = swz / (8 * NZ);
    const int rem   = swz % (8 * NZ);
    const int nt    = rem & 7;
    const int z     = rem >> 3;

    const unsigned short* W = (z == 0) ? W0 : ((z == 1) ? W1 : W2);
    const float* bias       = (z == 0) ? b0 : ((z == 1) ? b1 : b2);
    void* out               = (z == 0) ? o0 : ((z == 1) ? o1 : o2);
    const bool phi = z < nphi;

    const int tid  = threadIdx.x;
    const int lane = tid & 63;
    const int w    = tid >> 6;
    const int wr   = w >> 1, wc = w & 1;
    const int m0   = mt * 128;
    const int n0   = nt * 128;

    // staging: per call a wave deposits 8 rows x 128B; row&7 == lane>>3.
    const int srow = w * 8 + (lane >> 3);                // row in 32-row chunk
    const int csw  = ((lane & 7) ^ (lane >> 3)) * 8;     // pre-swizzled k-chunk
    const int rsel = lane & 15;
    const int kq   = lane >> 4;                          // 0..3

    f32x4 acc[4][4] = {};

    for (int kt = 0; kt < 16; ++kt) {
        const int k0 = kt * 64;
#pragma unroll
        for (int c = 0; c < 4; ++c) {
            const int r = c * 32 + srow;
            gload16(&A[(size_t)(m0 + r) * E_DIM + k0 + csw], &As[(c * 32 + w * 8) * 64]);
            gload16(&W[(size_t)(n0 + r) * E_DIM + k0 + csw], &Bs[(c * 32 + w * 8) * 64]);
        }
        __syncthreads();
#pragma unroll
        for (int kk = 0; kk < 2; ++kk) {
            const int kx = ((kk * 4 + kq) ^ (lane & 7)) * 8; // swizzled read
            short8 af[4], bf[4];
#pragma unroll
            for (int mi = 0; mi < 4; ++mi)
                af[mi] = *(const short8*)&As[(wr * 64 + mi * 16 + rsel) * 64 + kx];
#pragma unroll
            for (int ni = 0; ni < 4; ++ni)
                bf[ni] = *(const short8*)&Bs[(wc * 64 + ni * 16 + rsel) * 64 + kx];
            __builtin_amdgcn_s_setprio(1);
#pragma unroll
            for (int mi = 0; mi < 4; ++mi)
#pragma unroll
                for (int ni = 0; ni < 4; ++ni)
                    acc[mi][ni] = __builtin_amdgcn_mfma_f32_16x16x32_bf16(
                        af[mi], bf[ni], acc[mi][ni], 0, 0, 0);
            __builtin_amdgcn_s_setprio(0);
        }
        __syncthreads();
    }

    // epilogue: C/D layout col=lane&15, row=(lane>>4)*4+r
#pragma unroll
    for (int mi = 0; mi < 4; ++mi) {
        const int rbase = m0 + wr * 64 + mi * 16 + ((lane >> 4) << 2);
#pragma unroll
        for (int ni = 0; ni < 4; ++ni) {
            const int col = n0 + wc * 64 + ni * 16 + (lane & 15);
            const float bv = bias[col];
#pragma unroll
            for (int r = 0; r < 4; ++r) {
                float v = acc[mi][ni][r] + bv;
                if (phi) v = (v > 0.f) ? (v + 1.f) : __expf(v); // elu(v)+1
                if (OUTF32)
                    ((float*)out)[(size_t)(rbase + r) * E_DIM + col] = v;
                else
                    ((unsigned short*)out)[(size_t)(rbase + r) * E_DIM + col] = f2b(v);
            }
        }
    }
}

// ---------------------------------------------------------------------------
// kv_outer: per (b,h,split) partial S^T[j][i] = sum_l phiK[l,i]*V[l,j], Z[i].
// ---------------------------------------------------------------------------
__global__ __launch_bounds__(256) void kv_outer(
    const unsigned short* __restrict__ K, const unsigned short* __restrict__ V,
    float* __restrict__ Sp, float* __restrict__ Zp)
{
    __shared__ float kb[8][64];
    __shared__ float vb[8][64];
    const int split = blockIdx.x;
    const int bh    = blockIdx.y;
    const int b = bh >> 4, h = bh & 15;
    const int t  = threadIdx.x;
    const int i0 = (t & 15) * 4;
    const int j0 = (t >> 4) * 4;
    const int sr = t >> 5;
    const int sc = (t & 31) * 4;

    const unsigned short* sbase = (sc < 64) ? K : V;
    size_t gbase = ((size_t)(b * LSEQ + split * ROWS_PER_SPLIT)) * E_DIM + h * DH;

    f32x4 acc[4] = {};
    f32x4 zacc = {};

    for (int chunk = 0; chunk < ROWS_PER_SPLIT / 8; ++chunk) {
        us4 u = *(const us4*)&sbase[gbase + (size_t)sr * E_DIM + (sc & 63)];
        f32x4 fv = { b2f(u.x), b2f(u.y), b2f(u.z), b2f(u.w) };
        float* dst = (sc < 64) ? &kb[sr][sc] : &vb[sr][sc - 64];
        *(f32x4*)dst = fv;
        __syncthreads();
#pragma unroll
        for (int rr = 0; rr < 8; ++rr) {
            f32x4 kv = *(const f32x4*)&kb[rr][i0];
            f32x4 vv = *(const f32x4*)&vb[rr][j0];
            acc[0] += kv * vv.x;
            acc[1] += kv * vv.y;
            acc[2] += kv * vv.z;
            acc[3] += kv * vv.w;
            if ((t >> 4) == 0) zacc += kv;
        }
        __syncthreads();
        gbase += (size_t)8 * E_DIM;
    }

    const size_t sb = ((size_t)bh * NSPLIT + split) * (DH * DH);
#pragma unroll
    for (int jj = 0; jj < 4; ++jj)
        *(f32x4*)&Sp[sb + (size_t)(j0 + jj) * DH + i0] = acc[jj];
    if ((t >> 4) == 0)
        *(f32x4*)&Zp[((size_t)bh * NSPLIT + split) * DH + i0] = zacc;
}

// ---------------------------------------------------------------------------
// ctx_kernel: per (b,h): B-tile = [S^T (64 rows) | Z (row 64) | zeros]
// bf16 in LDS. num+denom via MFMA (5 n-frags); ctx = num/(denom+eps).
// ---------------------------------------------------------------------------
__global__ __launch_bounds__(256) void ctx_kernel(
    const unsigned short* __restrict__ Q, const float* __restrict__ Sp,
    const float* __restrict__ Zp, unsigned short* __restrict__ ctx)
{
    __shared__ unsigned short Bs[80 * 64];
    const int bh = blockIdx.y;
    const int b = bh >> 4, h = bh & 15;
    const int t    = threadIdx.x;
    const int lane = t & 63;
    const int w    = t >> 6;

    for (int e = t; e < 4096; e += 256) {
        float s = 0.f;
#pragma unroll
        for (int p = 0; p < NSPLIT; ++p)
            s += Sp[((size_t)bh * NSPLIT + p) * (DH * DH) + e];
        Bs[e] = f2b(s);
    }
    if (t < 64) {
        float zv = 0.f;
#pragma unroll
        for (int p = 0; p < NSPLIT; ++p)
            zv += Zp[((size_t)bh * NSPLIT + p) * DH + t];
        Bs[64 * 64 + t] = f2b(zv);
    }
    for (int e = t; e < 15 * 64; e += 256) Bs[65 * 64 + e] = 0;
    __syncthreads();

    const int m0 = blockIdx.x * 256 + w * 64;
    f32x4 acc[4][5] = {};
#pragma unroll
    for (int kk = 0; kk < 2; ++kk) {
        const int krd = kk * 32 + (lane >> 4) * 8;
        short8 af[4];
#pragma unroll
        for (int mi = 0; mi < 4; ++mi) {
            const int l = m0 + mi * 16 + (lane & 15);
            af[mi] = *(const short8*)&Q[((size_t)(b * LSEQ + l)) * E_DIM + h * DH + krd];
        }
#pragma unroll
        for (int ni = 0; ni < 5; ++ni) {
            short8 bfr = *(const short8*)&Bs[(ni * 16 + (lane & 15)) * 64 + krd];
#pragma unroll
            for (int mi = 0; mi < 4; ++mi)
                acc[mi][ni] = __builtin_amdgcn_mfma_f32_16x16x32_bf16(
                    af[mi], bfr, acc[mi][ni], 0, 0, 0);
        }
    }
#pragma unroll
    for (int mi = 0; mi < 4; ++mi) {
#pragma unroll
        for (int r = 0; r < 4; ++r) {
            const float dv  = __shfl(acc[mi][4][r], lane & 48, 64); // denom (col 64)
            const float inv = 1.f / (dv + 1e-6f);
            const int l = m0 + mi * 16 + ((lane >> 4) << 2) + r;
#pragma unroll
            for (int ni = 0; ni < 4; ++ni)
                ctx[((size_t)(b * LSEQ + l)) * E_DIM + h * DH + ni * 16 + (lane & 15)] =
                    f2b(acc[mi][ni][r] * inv);
        }
    }
}

// ---------------------------------------------------------------------------
extern "C" void kernel_launch(void* const* d_in, const int* in_sizes, int n_in,
                              void* d_out, int out_size, void* d_ws, size_t ws_size,
                              hipStream_t stream)
{
    const float* query = (const float*)d_in[0];
    const float* Wq = (const float*)d_in[1];
    const float* bq = (const float*)d_in[2];
    const float* Wk = (const float*)d_in[3];
    const float* bk = (const float*)d_in[4];
    const float* Wv = (const float*)d_in[5];
    const float* bv = (const float*)d_in[6];
    const float* Wo = (const float*)d_in[7];
    const float* bo = (const float*)d_in[8];

    // ws (136 MiB peak):
    //   [qb 32MiB | Wob 2 | Wqb 2 | Wkb 2 | Wvb 2 | phiQ 32 | phiK 32 | Vw 32]
    //   Sp/Zp (16.25 MiB) alias qb after gemm1; ctx aliases phiK.
    unsigned short* qb   = (unsigned short*)d_ws;
    unsigned short* Wob  = qb  + (size_t)NTOK * E_DIM;
    unsigned short* Wqb  = Wob + (size_t)E_DIM * E_DIM;
    unsigned short* Wkb  = Wqb + (size_t)E_DIM * E_DIM;
    unsigned short* Wvb  = Wkb + (size_t)E_DIM * E_DIM;
    unsigned short* phiQ = Wvb + (size_t)E_DIM * E_DIM;
    unsigned short* phiK = phiQ + (size_t)NTOK * E_DIM;
    unsigned short* Vw   = phiK + (size_t)NTOK * E_DIM;
    float* Sp = (float*)qb;                           // [64][NSPLIT][64*64] f32
    float* Zp = Sp + (size_t)64 * NSPLIT * DH * DH;   // [64][NSPLIT][64] f32
    unsigned short* ctx = phiK;                       // phiK dead after kv_outer

    // 0) fp32 -> bf16 (query + 4 weights, one dispatch)
    cvt_all<<<dim3(2048 + 4 * 128), 256, 0, stream>>>(query, Wq, Wk, Wv, Wo,
                                                      qb, Wqb, Wkb, Wvb, Wob);
    // 1) QKV projections (+phi on Q,K) -> bf16; 128 m-tiles x 8 n-tiles x 3
    gemm128<false, 3><<<dim3(3072), 256, 0, stream>>>(qb, Wqb, Wkb, Wvb,
                                                      bq, bk, bv,
                                                      phiQ, phiK, Vw, 2);
    // 2) S^T/Z partials (Sp/Zp overwrite dead qb)
    kv_outer<<<dim3(NSPLIT, 64), 256, 0, stream>>>(phiK, Vw, Sp, Zp);
    // 3) context -> bf16
    ctx_kernel<<<dim3(LSEQ / 256, 64), 256, 0, stream>>>(phiQ, Sp, Zp, ctx);
    // 4) output projection -> FP32 d_out; 128 x 8 tiles
    gemm128<true, 1><<<dim3(1024), 256, 0, stream>>>(ctx, Wob, Wob, Wob,
                                                     bo, bo, bo,
                                                     d_out, d_out, d_out, 0);
}

// Round 11
// 231.815 us; speedup vs baseline: 1.5714x; 1.0659x over previous
//
#include <hip/hip_runtime.h>
#include <stdint.h>

// ---------------------------------------------------------------------------
// TTLinearAttention on MI355X. Inputs fp32, output fp32.
// Round 11: R10 + factor the 16-way Sp re-reduction OUT of ctx_kernel.
// reduce_S sums partials once (16 MB read) into a prebuilt bf16 [S^T|Z|0]
// 80x64 tile per (b,h); ctx stages it with one 10KB vector copy (was: every
// one of 1024 blocks re-reading 256KB of Sp = 256MB/dispatch).
// GEMM = proven m97 2-barrier 128^2 structure, T1+T2, 5 blocks/CU (949 TF).
// ---------------------------------------------------------------------------

typedef __attribute__((ext_vector_type(8))) short short8;
typedef __attribute__((ext_vector_type(4))) float f32x4;
typedef __attribute__((ext_vector_type(4))) unsigned short us4;
typedef __attribute__((ext_vector_type(8))) unsigned short us8;

#define E_DIM 1024
#define LSEQ 4096
#define NTOK 16384
#define DH 64
#define NSPLIT 16
#define ROWS_PER_SPLIT (LSEQ / NSPLIT) // 256

__device__ __forceinline__ float b2f(unsigned short u) {
    return __builtin_bit_cast(float, (uint32_t)u << 16);
}
__device__ __forceinline__ unsigned short f2b(float f) {
    uint32_t x = __builtin_bit_cast(uint32_t, f);
    x += 0x7FFFu + ((x >> 16) & 1u); // round-to-nearest-even
    return (unsigned short)(x >> 16);
}
__device__ __forceinline__ void gload16(const void* g, void* l) {
    __builtin_amdgcn_global_load_lds(
        (const __attribute__((address_space(1))) void*)g,
        (__attribute__((address_space(3))) void*)l, 16, 0, 0);
}

// ---------------------------------------------------------------------------
// cvt_all: one dispatch converts query (blocks 0..2047) and the 4 weight
// matrices (128 blocks each). Every thread: 4 x us8 groups (8192 B/block).
// ---------------------------------------------------------------------------
__global__ __launch_bounds__(256) void cvt_all(
    const float* __restrict__ q,
    const float* __restrict__ w0, const float* __restrict__ w1,
    const float* __restrict__ w2, const float* __restrict__ w3,
    unsigned short* __restrict__ dq,
    unsigned short* __restrict__ d0, unsigned short* __restrict__ d1,
    unsigned short* __restrict__ d2, unsigned short* __restrict__ d3)
{
    const int bid = blockIdx.x;
    const float* s;
    unsigned short* d;
    int base;
    if (bid < 2048) {
        s = q; d = dq; base = bid * 1024;
    } else {
        const int k = (bid - 2048) >> 7;
        s = (k == 0) ? w0 : (k == 1) ? w1 : (k == 2) ? w2 : w3;
        d = (k == 0) ? d0 : (k == 1) ? d1 : (k == 2) ? d2 : d3;
        base = ((bid - 2048) & 127) * 1024;
    }
#pragma unroll
    for (int j = 0; j < 4; ++j) {
        const int i = base + j * 256 + threadIdx.x;
        f32x4 a = ((const f32x4*)s)[(size_t)i * 2];
        f32x4 b = ((const f32x4*)s)[(size_t)i * 2 + 1];
        us8 o = { f2b(a.x), f2b(a.y), f2b(a.z), f2b(a.w),
                  f2b(b.x), f2b(b.y), f2b(b.z), f2b(b.w) };
        ((us8*)d)[i] = o;
    }
}

// ---------------------------------------------------------------------------
// gemm128: C[m,n] = phi?( sum_k A[m,k] * W[n,k] + bias[n] )   (bias fp32)
// m97 structure: 128x128 tile, BK=64, 256 threads = 4 waves (2x2), wave tile
// 64x64. LDS 32KB single-buffer; per K-tile: stage (8 gload16) -> sync ->
// 16 swizzled ds_read_b128 + 32 MFMA -> sync. ~5 blocks/CU hide the drain.
// T2 swizzle: LDS[row][chunk]=global[row][chunk^(row&7)] (16B chunks);
// stage pre-swizzles source (lane&7)^(lane>>3); read XORs chunk with lane&7.
// Grid 1D XCD-swizzled: m slowest, (n,z) fastest (R6 decode).
// ---------------------------------------------------------------------------
template <bool OUTF32, int NZ>
__global__ __launch_bounds__(256, 4) void gemm128(
    const unsigned short* __restrict__ A,
    const unsigned short* __restrict__ W0, const unsigned short* __restrict__ W1,
    const unsigned short* __restrict__ W2,
    const float* __restrict__ b0, const float* __restrict__ b1,
    const float* __restrict__ b2,
    void* __restrict__ o0, void* __restrict__ o1, void* __restrict__ o2,
    int nphi)
{
    __shared__ unsigned short As[128 * 64];
    __shared__ unsigned short Bs[128 * 64];

    // --- T1 XCD swizzle (bijective: nwg = 128*8*NZ, divisible by 8) ---
    const int bid   = blockIdx.x;
    const int chunk = (128 * 8 * NZ) / 8;
    const int swz   = (bid & 7) * chunk + (bid >> 3);
    const int mt    = swz / (8 * NZ);
    const int rem   = swz % (8 * NZ);
    const int nt    = rem & 7;
    const int z     = rem >> 3;

    const unsigned short* W = (z == 0) ? W0 : ((z == 1) ? W1 : W2);
    const float* bias       = (z == 0) ? b0 : ((z == 1) ? b1 : b2);
    void* out               = (z == 0) ? o0 : ((z == 1) ? o1 : o2);
    const bool phi = z < nphi;

    const int tid  = threadIdx.x;
    const int lane = tid & 63;
    const int w    = tid >> 6;
    const int wr   = w >> 1, wc = w & 1;
    const int m0   = mt * 128;
    const int n0   = nt * 128;

    // staging: per call a wave deposits 8 rows x 128B; row&7 == lane>>3.
    const int srow = w * 8 + (lane >> 3);                // row in 32-row chunk
    const int csw  = ((lane & 7) ^ (lane >> 3)) * 8;     // pre-swizzled k-chunk
    const int rsel = lane & 15;
    const int kq   = lane >> 4;                          // 0..3

    f32x4 acc[4][4] = {};

    for (int kt = 0; kt < 16; ++kt) {
        const int k0 = kt * 64;
#pragma unroll
        for (int c = 0; c < 4; ++c) {
            const int r = c * 32 + srow;
            gload16(&A[(size_t)(m0 + r) * E_DIM + k0 + csw], &As[(c * 32 + w * 8) * 64]);
            gload16(&W[(size_t)(n0 + r) * E_DIM + k0 + csw], &Bs[(c * 32 + w * 8) * 64]);
        }
        __syncthreads();
#pragma unroll
        for (int kk = 0; kk < 2; ++kk) {
            const int kx = ((kk * 4 + kq) ^ (lane & 7)) * 8; // swizzled read
            short8 af[4], bf[4];
#pragma unroll
            for (int mi = 0; mi < 4; ++mi)
                af[mi] = *(const short8*)&As[(wr * 64 + mi * 16 + rsel) * 64 + kx];
#pragma unroll
            for (int ni = 0; ni < 4; ++ni)
                bf[ni] = *(const short8*)&Bs[(wc * 64 + ni * 16 + rsel) * 64 + kx];
            __builtin_amdgcn_s_setprio(1);
#pragma unroll
            for (int mi = 0; mi < 4; ++mi)
#pragma unroll
                for (int ni = 0; ni < 4; ++ni)
                    acc[mi][ni] = __builtin_amdgcn_mfma_f32_16x16x32_bf16(
                        af[mi], bf[ni], acc[mi][ni], 0, 0, 0);
            __builtin_amdgcn_s_setprio(0);
        }
        __syncthreads();
    }

    // epilogue: C/D layout col=lane&15, row=(lane>>4)*4+r
#pragma unroll
    for (int mi = 0; mi < 4; ++mi) {
        const int rbase = m0 + wr * 64 + mi * 16 + ((lane >> 4) << 2);
#pragma unroll
        for (int ni = 0; ni < 4; ++ni) {
            const int col = n0 + wc * 64 + ni * 16 + (lane & 15);
            const float bv = bias[col];
#pragma unroll
            for (int r = 0; r < 4; ++r) {
                float v = acc[mi][ni][r] + bv;
                if (phi) v = (v > 0.f) ? (v + 1.f) : __expf(v); // elu(v)+1
                if (OUTF32)
                    ((float*)out)[(size_t)(rbase + r) * E_DIM + col] = v;
                else
                    ((unsigned short*)out)[(size_t)(rbase + r) * E_DIM + col] = f2b(v);
            }
        }
    }
}

// ---------------------------------------------------------------------------
// kv_outer: per (b,h,split) partial S^T[j][i] = sum_l phiK[l,i]*V[l,j], Z[i].
// ---------------------------------------------------------------------------
__global__ __launch_bounds__(256) void kv_outer(
    const unsigned short* __restrict__ K, const unsigned short* __restrict__ V,
    float* __restrict__ Sp, float* __restrict__ Zp)
{
    __shared__ float kb[8][64];
    __shared__ float vb[8][64];
    const int split = blockIdx.x;
    const int bh    = blockIdx.y;
    const int b = bh >> 4, h = bh & 15;
    const int t  = threadIdx.x;
    const int i0 = (t & 15) * 4;
    const int j0 = (t >> 4) * 4;
    const int sr = t >> 5;
    const int sc = (t & 31) * 4;

    const unsigned short* sbase = (sc < 64) ? K : V;
    size_t gbase = ((size_t)(b * LSEQ + split * ROWS_PER_SPLIT)) * E_DIM + h * DH;

    f32x4 acc[4] = {};
    f32x4 zacc = {};

    for (int chunk = 0; chunk < ROWS_PER_SPLIT / 8; ++chunk) {
        us4 u = *(const us4*)&sbase[gbase + (size_t)sr * E_DIM + (sc & 63)];
        f32x4 fv = { b2f(u.x), b2f(u.y), b2f(u.z), b2f(u.w) };
        float* dst = (sc < 64) ? &kb[sr][sc] : &vb[sr][sc - 64];
        *(f32x4*)dst = fv;
        __syncthreads();
#pragma unroll
        for (int rr = 0; rr < 8; ++rr) {
            f32x4 kv = *(const f32x4*)&kb[rr][i0];
            f32x4 vv = *(const f32x4*)&vb[rr][j0];
            acc[0] += kv * vv.x;
            acc[1] += kv * vv.y;
            acc[2] += kv * vv.z;
            acc[3] += kv * vv.w;
            if ((t >> 4) == 0) zacc += kv;
        }
        __syncthreads();
        gbase += (size_t)8 * E_DIM;
    }

    const size_t sb = ((size_t)bh * NSPLIT + split) * (DH * DH);
#pragma unroll
    for (int jj = 0; jj < 4; ++jj)
        *(f32x4*)&Sp[sb + (size_t)(j0 + jj) * DH + i0] = acc[jj];
    if ((t >> 4) == 0)
        *(f32x4*)&Zp[((size_t)bh * NSPLIT + split) * DH + i0] = zacc;
}

// ---------------------------------------------------------------------------
// reduce_S: sum the NSPLIT partials ONCE per (b,h) into a prebuilt bf16
// B-tile [S^T (64 rows) | Z (row 64) | zeros (rows 65..79)] -> Sred[bh][5120].
// Grid (4 chunks, 64 bh); chunk c handles e in [c*1024, (c+1)*1024).
// ---------------------------------------------------------------------------
__global__ __launch_bounds__(256) void reduce_S(
    const float* __restrict__ Sp, const float* __restrict__ Zp,
    unsigned short* __restrict__ Sred)
{
    const int c  = blockIdx.x;  // 0..3
    const int bh = blockIdx.y;  // 0..63
    const int t  = threadIdx.x;
    unsigned short* dst = Sred + (size_t)bh * (80 * 64);

#pragma unroll
    for (int j = 0; j < 4; ++j) {
        const int e = c * 1024 + j * 256 + t;
        float s = 0.f;
#pragma unroll
        for (int p = 0; p < NSPLIT; ++p)
            s += Sp[((size_t)bh * NSPLIT + p) * (DH * DH) + e];
        dst[e] = f2b(s);
    }
    if (c == 0) {
        if (t < 64) {
            float zv = 0.f;
#pragma unroll
            for (int p = 0; p < NSPLIT; ++p)
                zv += Zp[((size_t)bh * NSPLIT + p) * DH + t];
            dst[64 * 64 + t] = f2b(zv);
        }
        for (int e = t; e < 15 * 64; e += 256) dst[65 * 64 + e] = 0;
    }
}

// ---------------------------------------------------------------------------
// ctx_kernel: per (b,h): copy prebuilt B-tile (10KB) into LDS, then
// num+denom via MFMA (5 n-frags, K=64); ctx = num/(denom+eps).
// Each block: 256 rows of phiQ (wave w -> 64 rows).
// ---------------------------------------------------------------------------
__global__ __launch_bounds__(256) void ctx_kernel(
    const unsigned short* __restrict__ Q, const unsigned short* __restrict__ Sred,
    unsigned short* __restrict__ ctx)
{
    __shared__ unsigned short Bs[80 * 64];
    const int bh = blockIdx.y;
    const int b = bh >> 4, h = bh & 15;
    const int t    = threadIdx.x;
    const int lane = t & 63;
    const int w    = t >> 6;

    {
        const us8* src = (const us8*)(Sred + (size_t)bh * (80 * 64));
        us8* dstl = (us8*)Bs;
        for (int i = t; i < 640; i += 256) dstl[i] = src[i];
    }
    __syncthreads();

    const int m0 = blockIdx.x * 256 + w * 64;
    f32x4 acc[4][5] = {};
#pragma unroll
    for (int kk = 0; kk < 2; ++kk) {
        const int krd = kk * 32 + (lane >> 4) * 8;
        short8 af[4];
#pragma unroll
        for (int mi = 0; mi < 4; ++mi) {
            const int l = m0 + mi * 16 + (lane & 15);
            af[mi] = *(const short8*)&Q[((size_t)(b * LSEQ + l)) * E_DIM + h * DH + krd];
        }
#pragma unroll
        for (int ni = 0; ni < 5; ++ni) {
            short8 bfr = *(const short8*)&Bs[(ni * 16 + (lane & 15)) * 64 + krd];
#pragma unroll
            for (int mi = 0; mi < 4; ++mi)
                acc[mi][ni] = __builtin_amdgcn_mfma_f32_16x16x32_bf16(
                    af[mi], bfr, acc[mi][ni], 0, 0, 0);
        }
    }
#pragma unroll
    for (int mi = 0; mi < 4; ++mi) {
#pragma unroll
        for (int r = 0; r < 4; ++r) {
            const float dv  = __shfl(acc[mi][4][r], lane & 48, 64); // denom (col 64)
            const float inv = 1.f / (dv + 1e-6f);
            const int l = m0 + mi * 16 + ((lane >> 4) << 2) + r;
#pragma unroll
            for (int ni = 0; ni < 4; ++ni)
                ctx[((size_t)(b * LSEQ + l)) * E_DIM + h * DH + ni * 16 + (lane & 15)] =
                    f2b(acc[mi][ni][r] * inv);
        }
    }
}

// ---------------------------------------------------------------------------
extern "C" void kernel_launch(void* const* d_in, const int* in_sizes, int n_in,
                              void* d_out, int out_size, void* d_ws, size_t ws_size,
                              hipStream_t stream)
{
    const float* query = (const float*)d_in[0];
    const float* Wq = (const float*)d_in[1];
    const float* bq = (const float*)d_in[2];
    const float* Wk = (const float*)d_in[3];
    const float* bk = (const float*)d_in[4];
    const float* Wv = (const float*)d_in[5];
    const float* bv = (const float*)d_in[6];
    const float* Wo = (const float*)d_in[7];
    const float* bo = (const float*)d_in[8];

    // ws (136 MiB peak):
    //   [qb 32MiB | Wob 2 | Wqb 2 | Wkb 2 | Wvb 2 | phiQ 32 | phiK 32 | Vw 32]
    //   Sp/Zp (16.25 MiB) alias qb after gemm1; Sred (640KB) aliases Wqb;
    //   ctx aliases phiK.
    unsigned short* qb   = (unsigned short*)d_ws;
    unsigned short* Wob  = qb  + (size_t)NTOK * E_DIM;
    unsigned short* Wqb  = Wob + (size_t)E_DIM * E_DIM;
    unsigned short* Wkb  = Wqb + (size_t)E_DIM * E_DIM;
    unsigned short* Wvb  = Wkb + (size_t)E_DIM * E_DIM;
    unsigned short* phiQ = Wvb + (size_t)E_DIM * E_DIM;
    unsigned short* phiK = phiQ + (size_t)NTOK * E_DIM;
    unsigned short* Vw   = phiK + (size_t)NTOK * E_DIM;
    float* Sp = (float*)qb;                           // [64][NSPLIT][64*64] f32
    float* Zp = Sp + (size_t)64 * NSPLIT * DH * DH;   // [64][NSPLIT][64] f32
    unsigned short* Sred = Wqb;                       // [64][80*64] bf16
    unsigned short* ctx = phiK;                       // phiK dead after kv_outer

    // 0) fp32 -> bf16 (query + 4 weights, one dispatch)
    cvt_all<<<dim3(2048 + 4 * 128), 256, 0, stream>>>(query, Wq, Wk, Wv, Wo,
                                                      qb, Wqb, Wkb, Wvb, Wob);
    // 1) QKV projections (+phi on Q,K) -> bf16; 128 m-tiles x 8 n-tiles x 3
    gemm128<false, 3><<<dim3(3072), 256, 0, stream>>>(qb, Wqb, Wkb, Wvb,
                                                      bq, bk, bv,
                                                      phiQ, phiK, Vw, 2);
    // 2) S^T/Z partials (Sp/Zp overwrite dead qb)
    kv_outer<<<dim3(NSPLIT, 64), 256, 0, stream>>>(phiK, Vw, Sp, Zp);
    // 2b) sum partials once -> prebuilt bf16 B-tile per bh (overwrites Wqb)
    reduce_S<<<dim3(4, 64), 256, 0, stream>>>(Sp, Zp, Sred);
    // 3) context -> bf16
    ctx_kernel<<<dim3(LSEQ / 256, 64), 256, 0, stream>>>(phiQ, Sred, ctx);
    // 4) output projection -> FP32 d_out; 128 x 8 tiles
    gemm128<true, 1><<<dim3(1024), 256, 0, stream>>>(ctx, Wob, Wob, Wob,
                                                     bo, bo, bo,
                                                     d_out, d_out, d_out, 0);
}